// Round 10
// baseline (283.334 us; speedup 1.0000x reference)
//
#include <hip/hip_runtime.h>
#include <cstdint>

typedef __bf16 bf16;
typedef __bf16 bf16x8 __attribute__((ext_vector_type(8)));
typedef __bf16 bf16x4 __attribute__((ext_vector_type(4)));
typedef float  f32x4  __attribute__((ext_vector_type(4)));

#define HIDDEN 2304
#define NQ 2048
#define NKV 1024
#define SEQ 2048

typedef __attribute__((address_space(1))) void gv_t;
typedef __attribute__((address_space(3))) void lv_t;
__device__ __forceinline__ void gld16(const void* g, void* l) {
  __builtin_amdgcn_global_load_lds((gv_t*)g, (lv_t*)l, 16, 0, 0);
}

#define BAR()    asm volatile("s_barrier" ::: "memory")
#define LGKM(n)  asm volatile("s_waitcnt lgkmcnt(" #n ")" ::: "memory")
#define VM6()    asm volatile("s_waitcnt vmcnt(6)" ::: "memory")
#define VM2()    asm volatile("s_waitcnt vmcnt(2)" ::: "memory")
#define VM0()    asm volatile("s_waitcnt vmcnt(0)" ::: "memory")
#define SCHED0() __builtin_amdgcn_sched_barrier(0)

// ---------------- RMSNorm + bf16 cast ----------------
__global__ __launch_bounds__(256) void rmsnorm_kernel(const float* __restrict__ x,
                                                      const float* __restrict__ w,
                                                      bf16* __restrict__ xb) {
  const int row = blockIdx.x, t = threadIdx.x;
  const float* xr = x + (size_t)row * HIDDEN;
  float v[9]; float ss = 0.f;
#pragma unroll
  for (int i = 0; i < 9; ++i) { v[i] = xr[t + i * 256]; ss += v[i] * v[i]; }
#pragma unroll
  for (int o = 32; o; o >>= 1) ss += __shfl_xor(ss, o, 64);
  __shared__ float wss[4];
  if ((t & 63) == 0) wss[t >> 6] = ss;
  __syncthreads();
  ss = wss[0] + wss[1] + wss[2] + wss[3];
  const float rs = rsqrtf(ss * (1.0f / HIDDEN) + 1e-6f);
  bf16* xo = xb + (size_t)row * HIDDEN;
#pragma unroll
  for (int i = 0; i < 9; ++i) xo[t + i * 256] = (bf16)(v[i] * rs * (1.0f + w[t + i * 256]));
}

// ---------------- fused f32 -> bf16 weight convert (Wq,Wk,Wv,Wo) ----------
#define NW0 (2048 * 2304)
#define NW1 (1024 * 2304)
#define NW3 (2304 * 2048)
__global__ __launch_bounds__(256) void cvt4_kernel(const float* __restrict__ s0, const float* __restrict__ s1,
                                                   const float* __restrict__ s2, const float* __restrict__ s3,
                                                   bf16* __restrict__ d0, bf16* __restrict__ d1,
                                                   bf16* __restrict__ d2, bf16* __restrict__ d3) {
  int i = (blockIdx.x * 256 + threadIdx.x) * 4;
  const float* s; bf16* d;
  if (i < NW0) { s = s0; d = d0; }
  else if (i < NW0 + NW1) { s = s1; d = d1; i -= NW0; }
  else if (i < NW0 + 2 * NW1) { s = s2; d = d2; i -= NW0 + NW1; }
  else { s = s3; d = d3; i -= NW0 + 2 * NW1; }
  const float4 f = *(const float4*)(s + i);
  bf16x4 o; o.x = (bf16)f.x; o.y = (bf16)f.y; o.z = (bf16)f.z; o.w = (bf16)f.w;
  *(bf16x4*)(d + i) = o;
}

// ---------------- RoPE in-place on q and k (bf16) ----------------
__global__ __launch_bounds__(256) void rope_kernel(bf16* __restrict__ q, bf16* __restrict__ k,
                                                   const float* __restrict__ cosb,
                                                   const float* __restrict__ sinb) {
  const int tid = blockIdx.x * 256 + threadIdx.x;
  const int QN = 4096 * 8 * 128;
  const int KN = 4096 * 4 * 128;
  bf16* p; int row, d;
  if (tid < QN) {
    row = tid >> 10; const int rem = tid & 1023; d = rem & 127;
    p = q + (size_t)row * NQ + (rem >> 7) * 256 + d;
  } else {
    const int t2 = tid - QN; if (t2 >= KN) return;
    row = t2 >> 9; const int rem = t2 & 511; d = rem & 127;
    p = k + (size_t)row * NKV + (rem >> 7) * 256 + d;
  }
  const size_t cb = (size_t)row * 256 + d;
  const float c0 = cosb[cb], s0 = sinb[cb], c1 = cosb[cb + 128], s1 = sinb[cb + 128];
  const float a = (float)p[0], b = (float)p[128];
  p[0]   = (bf16)(a * c0 - b * s0);
  p[128] = (bf16)(b * c1 + a * s1);
}

// ======== 256x256 8-phase GEMM (QKV) — unchanged from round 8/9 ========
__device__ __forceinline__ void stage_half(const char* gbase, int stride, char* ldshalf, int tid) {
  const int c2 = ((tid & 7) * 16) ^ (((tid >> 3) & 7) << 4);  // pre-swizzled global col
#pragma unroll
  for (int q = 0; q < 2; ++q) {
    const int r = q * 64 + (tid >> 3);
    gld16(gbase + (size_t)r * stride + c2, ldshalf + q * 8192 + tid * 16);
  }
}

template<int MH, int NH, int KS>
__device__ __forceinline__ void mfma_burst(const bf16x8 (&af)[4][2], const bf16x8 (&bn)[2][2],
                                           f32x4 (&acc)[8][4]) {
  __builtin_amdgcn_s_setprio(1);
#pragma unroll
  for (int m = 0; m < 4; ++m)
#pragma unroll
    for (int n = 0; n < 2; ++n)
      acc[MH * 4 + m][NH * 2 + n] =
          __builtin_amdgcn_mfma_f32_16x16x32_bf16(af[m][KS], bn[n][KS], acc[MH * 4 + m][NH * 2 + n], 0, 0, 0);
  __builtin_amdgcn_s_setprio(0);
}

// MODE 0: fused QKV epilogue (N=4096: Q | K | V^T regions, 256-aligned).
template<int NT, int NY, int MODE>
__global__ __launch_bounds__(512) void gemm8p(const bf16* __restrict__ A, const bf16* __restrict__ B,
                                              bf16* __restrict__ Cq, bf16* __restrict__ Ck,
                                              bf16* __restrict__ Cvt, float* __restrict__ fo,
                                              const float* __restrict__ resid, int Nd) {
  __shared__ char lds[131072];
  const int Ks = NT * 128;  // row stride in BYTES
  const char* Aby = (const char*)A;
  const char* Bby = (const char*)B;

  int wg = blockIdx.x;
  const int chunk = (int)gridDim.x >> 3;
  wg = (wg & 7) * chunk + (wg >> 3);              // XCD-bijective swizzle (grid%8==0)
  const int by = wg % NY, bx = wg / NY;
  const int m0 = bx * 256, n0 = by * 256;

  const int tid = threadIdx.x, lane = tid & 63, wv = tid >> 6;
  const int wm = wv >> 2, wn = wv & 3;
  const int r16 = lane & 15, g = lane >> 4;
  const int xr = (r16 & 7) << 4;
  const int cb0 = (g * 16) ^ xr, cb1 = (64 + g * 16) ^ xr;
  const int rdA = wm * 16384 + r16 * 128;
  const int rdB = 32768 + (wn >> 1) * 16384 + (wn & 1) * 8192 + r16 * 128;

  const char* A0g = Aby + (size_t)m0 * Ks;
  const char* A1g = Aby + (size_t)(m0 + 128) * Ks;
  const char* B0g = Bby + (size_t)n0 * Ks;
  const char* B1g = Bby + (size_t)(n0 + 128) * Ks;

  f32x4 acc[8][4] = {};
  bf16x8 a0[4][2], a1[4][2], bb01[2][2], bb23[2][2];

  auto read_a0bb01 = [&](const char* buf) {
#pragma unroll
    for (int n = 0; n < 2; ++n) bb01[n][0] = *(const bf16x8*)(buf + rdB + n * 2048 + cb0);
#pragma unroll
    for (int n = 0; n < 2; ++n) bb01[n][1] = *(const bf16x8*)(buf + rdB + n * 2048 + cb1);
#pragma unroll
    for (int m = 0; m < 4; ++m) a0[m][0] = *(const bf16x8*)(buf + rdA + m * 2048 + cb0);
#pragma unroll
    for (int m = 0; m < 4; ++m) a0[m][1] = *(const bf16x8*)(buf + rdA + m * 2048 + cb1);
  };

  stage_half(A0g, Ks, lds + 0,     tid);
  stage_half(A1g, Ks, lds + 16384, tid);
  stage_half(B0g, Ks, lds + 32768, tid);
  stage_half(B1g, Ks, lds + 49152, tid);
  stage_half(B0g + 128, Ks, lds + 65536 + 32768, tid);
  stage_half(A0g + 128, Ks, lds + 65536 + 0,     tid);
  stage_half(A1g + 128, Ks, lds + 65536 + 16384, tid);
  VM6(); BAR();
  read_a0bb01(lds);  // tile 0

  for (int t = 0; t < NT; ++t) {
    const char* bufc = lds + (size_t)(t & 1) * 65536;
    char* bufn = lds + (size_t)((t + 1) & 1) * 65536;
    char* bufs = lds + (size_t)(t & 1) * 65536;
    // ---- P1: a0/bb01 ready; issue bb23 then a1; G1 ----
    LGKM(0);
#pragma unroll
    for (int n = 0; n < 2; ++n) bb23[n][0] = *(const bf16x8*)(bufc + rdB + (2 + n) * 2048 + cb0);
#pragma unroll
    for (int n = 0; n < 2; ++n) bb23[n][1] = *(const bf16x8*)(bufc + rdB + (2 + n) * 2048 + cb1);
#pragma unroll
    for (int m = 0; m < 4; ++m) a1[m][0] = *(const bf16x8*)(bufc + rdA + 8192 + m * 2048 + cb0);
#pragma unroll
    for (int m = 0; m < 4; ++m) a1[m][1] = *(const bf16x8*)(bufc + rdA + 8192 + m * 2048 + cb1);
    SCHED0();
    mfma_burst<0, 0, 0>(a0, bb01, acc);
    mfma_burst<0, 0, 1>(a0, bb01, acc);
    SCHED0(); BAR();
    // ---- P2: bb23 ready; stage B1(t+1); G2 ----
    LGKM(8);
    if (t + 1 < NT)
      stage_half(B1g + (size_t)(t + 1) * 128, Ks, bufn + 49152, tid);
    SCHED0();
    mfma_burst<0, 1, 0>(a0, bb23, acc);
    mfma_burst<0, 1, 1>(a0, bb23, acc);
    SCHED0(); BAR();
    // ---- P3: a1 ready; stage B0(t+2); G3 ----
    LGKM(0);
    if (t + 2 < NT)
      stage_half(B0g + (size_t)(t + 2) * 128, Ks, bufs + 32768, tid);
    SCHED0();
    mfma_burst<1, 0, 0>(a1, bb01, acc);
    mfma_burst<1, 0, 1>(a1, bb01, acc);
    SCHED0(); BAR();
    // ---- P4: counted vmcnt confirms tile t+1; stage A0,A1(t+2); G4 ----
    if (t < NT - 2) { VM2(); } else if (t == NT - 2) { VM0(); }
    if (t + 2 < NT) {
      stage_half(A0g + (size_t)(t + 2) * 128, Ks, bufs + 0,     tid);
      stage_half(A1g + (size_t)(t + 2) * 128, Ks, bufs + 16384, tid);
    }
    SCHED0();
    mfma_burst<1, 1, 0>(a1, bb23, acc);
    mfma_burst<1, 1, 1>(a1, bb23, acc);
    SCHED0(); BAR();
    if (t + 1 < NT) read_a0bb01(bufn);  // read-ahead for next tile
  }

  const int mrow = m0 + wm * 128 + g * 4;
  const int ncol = n0 + wn * 64 + r16;
#pragma unroll
  for (int i = 0; i < 8; ++i)
#pragma unroll
    for (int j = 0; j < 4; ++j)
#pragma unroll
      for (int e = 0; e < 4; ++e) {
        const int m = mrow + i * 16 + e;
        const int n = ncol + j * 16;
        const float vv = acc[i][j][e];
        if constexpr (MODE == 0) {
          if (n0 < 2048) {
            Cq[(size_t)m * 2048 + n] = (bf16)vv;
          } else if (n0 < 3072) {
            Ck[(size_t)m * 1024 + (n - 2048)] = (bf16)vv;
          } else {
            const int b2 = m >> 11, s = m & 2047;
            Cvt[((size_t)b2 * 1024 + (n - 3072)) * SEQ + s] = (bf16)vv;
          }
        } else {
          fo[(size_t)m * Nd + n] = vv + resid[(size_t)m * Nd + n];
        }
      }
}

// ======== O-projection split-K=2: 128x128 2-phase (r2-proven structure) ========
// A = ag [4096][2048], B = wob [2304][2048]. Grid 1152 = 32(m) x 18(n) x 2(kz),
// 256 thr, 4 waves (2x2), LDS padded [128][72] (2-way conflicts, free).
// 36KB LDS + ~90 VGPR -> 4+ blocks/CU co-resident (m97 regime): cross-block
// overlap hides staging latency. Each kz writes a bf16 partial plane into the
// DEAD xb/wqkv workspace region; reduce_kernel sums + residual (deterministic,
// no atomics).
__global__ __launch_bounds__(256) void gemmsk(const bf16* __restrict__ A, const bf16* __restrict__ B,
                                              bf16* __restrict__ P) {
  __shared__ bf16 As[128][72];
  __shared__ bf16 Bs[128][72];
  const int t = threadIdx.x, lane = t & 63, w = t >> 6;
  const int wr = w >> 1, wc = w & 1;
  const int r16 = lane & 15, g = lane >> 4;
  int wg = blockIdx.x;
  wg = (wg & 7) * 144 + (wg >> 3);   // XCD-bijective (1152 % 8 == 0)
  const int bx = wg % 32, rem = wg / 32;
  const int by = rem % 18, kz = rem / 18;
  const int m0 = bx * 128, n0 = by * 128;
  const int kbeg = kz * 1024, kend = kbeg + 1024;
  f32x4 acc[4][4] = {};
  for (int k0 = kbeg; k0 < kend; k0 += 64) {
    __syncthreads();
#pragma unroll
    for (int it = 0; it < 4; ++it) {
      const int flat = it * 2048 + t * 8;
      const int row = flat >> 6, kk = flat & 63;
      *(bf16x8*)&As[row][kk] = *(const bf16x8*)&A[(size_t)(m0 + row) * 2048 + k0 + kk];
      *(bf16x8*)&Bs[row][kk] = *(const bf16x8*)&B[(size_t)(n0 + row) * 2048 + k0 + kk];
    }
    __syncthreads();
#pragma unroll
    for (int ks = 0; ks < 2; ++ks) {
      bf16x8 af[4], bfv[4];
#pragma unroll
      for (int i = 0; i < 4; ++i) {
        af[i]  = *(const bf16x8*)&As[wr * 64 + i * 16 + r16][ks * 32 + g * 8];
        bfv[i] = *(const bf16x8*)&Bs[wc * 64 + i * 16 + r16][ks * 32 + g * 8];
      }
#pragma unroll
      for (int i = 0; i < 4; ++i)
#pragma unroll
        for (int j = 0; j < 4; ++j)
          acc[i][j] = __builtin_amdgcn_mfma_f32_16x16x32_bf16(af[i], bfv[j], acc[i][j], 0, 0, 0);
    }
  }
  bf16* pp = P + (size_t)kz * 4096 * 2304;
#pragma unroll
  for (int i = 0; i < 4; ++i)
#pragma unroll
    for (int j = 0; j < 4; ++j) {
      const int mb = m0 + wr * 64 + i * 16 + g * 4;
      const int n = n0 + wc * 64 + j * 16 + r16;
#pragma unroll
      for (int e = 0; e < 4; ++e)
        pp[(size_t)(mb + e) * 2304 + n] = (bf16)acc[i][j][e];
    }
}

// out = p0 + p1 + hs (f32), vectorized x4. 9437184 elems.
__global__ __launch_bounds__(256) void reduce_kernel(const bf16* __restrict__ P,
                                                     const float* __restrict__ hs,
                                                     float* __restrict__ out) {
  const int i = (blockIdx.x * 256 + threadIdx.x) * 4;
  const bf16x4 p0 = *(const bf16x4*)&P[i];
  const bf16x4 p1 = *(const bf16x4*)&P[9437184 + i];
  const float4 h = *(const float4*)&hs[i];
  float4 o;
  o.x = (float)p0.x + (float)p1.x + h.x;
  o.y = (float)p0.y + (float)p1.y + h.y;
  o.z = (float)p0.z + (float)p1.z + h.z;
  o.w = (float)p0.w + (float)p1.w + h.w;
  *(float4*)&out[i] = o;
}

// ---------------- attention tile loads (K 32x256, V^T 256x32) ----------------
__device__ __forceinline__ void attn_load(const bf16* __restrict__ kgp, const bf16* __restrict__ vgp,
                                          int j0, int t, bf16x8* kr, bf16x8* vr) {
#pragma unroll
  for (int it = 0; it < 4; ++it) {
    const int flat = it * 2048 + t * 8;
    kr[it] = *(const bf16x8*)&kgp[(size_t)((flat >> 8) + j0) * NKV + (flat & 255)];
    vr[it] = *(const bf16x8*)&vgp[(size_t)(flat >> 5) * SEQ + j0 + (flat & 31)];
  }
}

// ---------------- Flash attention: QT=64 (4 waves x 16 rows), KT=32 --------
__global__ __launch_bounds__(256) void attn_kernel(const bf16* __restrict__ q, const bf16* __restrict__ k,
                                                   const bf16* __restrict__ vt, bf16* __restrict__ ao) {
  __shared__ bf16 smem[21248];
  bf16* const qs  = smem;
  bf16* const ksl = smem;
  bf16* const vtl = smem + 8448;
  bf16* const pl  = smem + 18688;
  int qt = blockIdx.x;
  const int h = blockIdx.y, b = blockIdx.z;
  if (b) qt = 31 - qt;
  const int kvh = h >> 1;
  const int t = threadIdx.x, lane = t & 63, w = t >> 6;
  const int r16 = lane & 15, g = lane >> 4;
  const int i_base = qt * 64;

  {
    const bf16* qg = q + ((size_t)(b * SEQ + i_base)) * NQ + h * 256;
#pragma unroll
    for (int it = 0; it < 8; ++it) {
      const int flat = it * 2048 + t * 8;
      const int row = flat >> 8, dd = flat & 255;
      *(bf16x8*)&qs[row * 264 + dd] = *(const bf16x8*)&qg[(size_t)row * NQ + dd];
    }
  }
  __syncthreads();
  bf16x8 aq[8];
#pragma unroll
  for (int c = 0; c < 8; ++c) aq[c] = *(const bf16x8*)&qs[(w * 16 + r16) * 264 + c * 32 + g * 8];

  f32x4 oacc[16] = {};
  float lrun[4] = {0.f, 0.f, 0.f, 0.f};
  int jb = i_base - 1023; if (jb < 0) jb = 0; jb &= ~31;
  const int je = i_base + 63;
  const bf16* kg = k + (size_t)b * SEQ * NKV + kvh * 256;
  const bf16* vg = vt + ((size_t)b * NKV + kvh * 256) * SEQ;

  bf16x8 kr[4], vr[4];
  attn_load(kg, vg, jb, t, kr, vr);

  for (int j0 = jb; j0 <= je; j0 += 32) {
    __syncthreads();
#pragma unroll
    for (int it = 0; it < 4; ++it) {
      const int flat = it * 2048 + t * 8;
      *(bf16x8*)&ksl[(flat >> 8) * 264 + (flat & 255)] = kr[it];
      *(bf16x8*)&vtl[(flat >> 5) * 40 + (flat & 31)] = vr[it];
    }
    __syncthreads();
    const int jn = (j0 + 32 <= je) ? (j0 + 32) : j0;
    attn_load(kg, vg, jn, t, kr, vr);

    f32x4 sc0 = {}, sc1 = {};
#pragma unroll
    for (int c = 0; c < 8; ++c) {
      const bf16x8 b0 = *(const bf16x8*)&ksl[r16 * 264 + c * 32 + g * 8];
      const bf16x8 b1 = *(const bf16x8*)&ksl[(16 + r16) * 264 + c * 32 + g * 8];
      sc0 = __builtin_amdgcn_mfma_f32_16x16x32_bf16(aq[c], b0, sc0, 0, 0, 0);
      sc1 = __builtin_amdgcn_mfma_f32_16x16x32_bf16(aq[c], b1, sc1, 0, 0, 0);
    }
    const bool full = (j0 + 31 <= i_base) && (i_base + 63 - j0 < 1024);
#pragma unroll
    for (int e = 0; e < 4; ++e) {
      const float t0 = __expf(sc0[e] * 0.0025f);
      const float t1 = __expf(sc1[e] * 0.0025f);
      float p0 = __expf(-100.0f / (t0 + 1.0f));
      float p1 = __expf(-100.0f / (t1 + 1.0f));
      if (!full) {
        const int irow = i_base + w * 16 + g * 4 + e;
        const int jg0 = j0 + r16, jg1 = j0 + 16 + r16;
        if (jg0 > irow || irow - jg0 >= 1024) p0 = 0.f;
        if (jg1 > irow || irow - jg1 >= 1024) p1 = 0.f;
      }
      const bf16 b0 = (bf16)p0, b1 = (bf16)p1;
      lrun[e] += (float)b0 + (float)b1;
      pl[w * 640 + (g * 4 + e) * 40 + r16] = b0;
      pl[w * 640 + (g * 4 + e) * 40 + 16 + r16] = b1;
    }
    const bf16x8 pa = *(const bf16x8*)&pl[w * 640 + r16 * 40 + g * 8];
#pragma unroll
    for (int nf = 0; nf < 16; ++nf) {
      const bf16x8 vb = *(const bf16x8*)&vtl[(nf * 16 + r16) * 40 + g * 8];
      oacc[nf] = __builtin_amdgcn_mfma_f32_16x16x32_bf16(pa, vb, oacc[nf], 0, 0, 0);
    }
  }
  float inv[4];
#pragma unroll
  for (int e = 0; e < 4; ++e) {
#pragma unroll
    for (int o = 1; o < 16; o <<= 1) lrun[e] += __shfl_xor(lrun[e], o, 64);
    inv[e] = 1.0f / lrun[e];
  }
  bf16* aor = ao + ((size_t)(b * SEQ + i_base + w * 16)) * NQ + h * 256;
#pragma unroll
  for (int nf = 0; nf < 16; ++nf)
#pragma unroll
    for (int e = 0; e < 4; ++e)
      aor[(size_t)(g * 4 + e) * NQ + nf * 16 + r16] = (bf16)(oacc[nf][e] * inv[e]);
}

extern "C" void kernel_launch(void* const* d_in, const int* in_sizes, int n_in,
                              void* d_out, int out_size, void* d_ws, size_t ws_size,
                              hipStream_t stream) {
  const float* hs   = (const float*)d_in[0];
  const float* cosb = (const float*)d_in[1];
  const float* sinb = (const float*)d_in[2];
  const float* rw   = (const float*)d_in[3];
  const float* Wq   = (const float*)d_in[4];
  const float* Wk   = (const float*)d_in[5];
  const float* Wv   = (const float*)d_in[6];
  const float* Wo   = (const float*)d_in[7];
  float* out = (float*)d_out;
  char* ws = (char*)d_ws;

  bf16* xb   = (bf16*)(ws);             // 4096x2304 (DEAD after QKV gemm)
  bf16* wqkv = (bf16*)(ws + 18874368);  // [4096][2304] (DEAD after QKV gemm)
  bf16* wkb  = wqkv + (size_t)2048 * 2304;
  bf16* wvb  = wqkv + (size_t)3072 * 2304;
  bf16* wob  = (bf16*)(ws + 37748736);  // 2304x2048
  bf16* qg   = (bf16*)(ws + 47185920);  // 4096x2048
  bf16* kg   = (bf16*)(ws + 63963136);  // 4096x1024
  bf16* vtg  = (bf16*)(ws + 72351744);  // [2][1024][2048]
  bf16* ag   = (bf16*)(ws + 80740352);  // 4096x2048
  bf16* part = (bf16*)(ws);             // 2 x [4096][2304] bf16 partials, reuses xb+wqkv

  rmsnorm_kernel<<<4096, 256, 0, stream>>>(hs, rw, xb);
  cvt4_kernel<<<(NW0 + 2 * NW1 + NW3) / 4 / 256, 256, 0, stream>>>(Wq, Wk, Wv, Wo, wqkv, wkb, wvb, wob);
  // QKV: M=4096, N=4096, K=2304 (NT=36), grid 16x16=256
  gemm8p<36, 16, 0><<<256, 512, 0, stream>>>(xb, wqkv, qg, kg, vtg, nullptr, nullptr, 4096);
  rope_kernel<<<(4096 * 8 * 128 + 4096 * 4 * 128) / 256, 256, 0, stream>>>(qg, kg, cosb, sinb);
  attn_kernel<<<dim3(32, 8, 2), 256, 0, stream>>>(qg, kg, vtg, ag);
  // O-proj split-K=2: 1152 blocks (4.5/CU), bf16 partials into dead xb/wqkv
  gemmsk<<<1152, 256, 0, stream>>>(ag, wob, part);
  // out = p0 + p1 + hs
  reduce_kernel<<<9216, 256, 0, stream>>>(part, hs, out);
}

// Round 11
// 262.144 us; speedup vs baseline: 1.0808x; 1.0808x over previous
//
#include <hip/hip_runtime.h>
#include <cstdint>

typedef __bf16 bf16;
typedef __bf16 bf16x8 __attribute__((ext_vector_type(8)));
typedef __bf16 bf16x4 __attribute__((ext_vector_type(4)));
typedef float  f32x4  __attribute__((ext_vector_type(4)));

#define HIDDEN 2304
#define NQ 2048
#define NKV 1024
#define SEQ 2048

typedef __attribute__((address_space(1))) void gv_t;
typedef __attribute__((address_space(3))) void lv_t;
__device__ __forceinline__ void gld16(const void* g, void* l) {
  __builtin_amdgcn_global_load_lds((gv_t*)g, (lv_t*)l, 16, 0, 0);
}

#define BAR()    asm volatile("s_barrier" ::: "memory")
#define LGKM(n)  asm volatile("s_waitcnt lgkmcnt(" #n ")" ::: "memory")
#define VM6()    asm volatile("s_waitcnt vmcnt(6)" ::: "memory")
#define VM4()    asm volatile("s_waitcnt vmcnt(4)" ::: "memory")
#define VM0()    asm volatile("s_waitcnt vmcnt(0)" ::: "memory")
#define SCHED0() __builtin_amdgcn_sched_barrier(0)

// ---------------- RMSNorm + bf16 cast ----------------
__global__ __launch_bounds__(256) void rmsnorm_kernel(const float* __restrict__ x,
                                                      const float* __restrict__ w,
                                                      bf16* __restrict__ xb) {
  const int row = blockIdx.x, t = threadIdx.x;
  const float* xr = x + (size_t)row * HIDDEN;
  float v[9]; float ss = 0.f;
#pragma unroll
  for (int i = 0; i < 9; ++i) { v[i] = xr[t + i * 256]; ss += v[i] * v[i]; }
#pragma unroll
  for (int o = 32; o; o >>= 1) ss += __shfl_xor(ss, o, 64);
  __shared__ float wss[4];
  if ((t & 63) == 0) wss[t >> 6] = ss;
  __syncthreads();
  ss = wss[0] + wss[1] + wss[2] + wss[3];
  const float rs = rsqrtf(ss * (1.0f / HIDDEN) + 1e-6f);
  bf16* xo = xb + (size_t)row * HIDDEN;
#pragma unroll
  for (int i = 0; i < 9; ++i) xo[t + i * 256] = (bf16)(v[i] * rs * (1.0f + w[t + i * 256]));
}

// ---------------- fused f32 -> bf16 weight convert (Wq,Wk,Wv,Wo) ----------
#define NW0 (2048 * 2304)
#define NW1 (1024 * 2304)
#define NW3 (2304 * 2048)
__global__ __launch_bounds__(256) void cvt4_kernel(const float* __restrict__ s0, const float* __restrict__ s1,
                                                   const float* __restrict__ s2, const float* __restrict__ s3,
                                                   bf16* __restrict__ d0, bf16* __restrict__ d1,
                                                   bf16* __restrict__ d2, bf16* __restrict__ d3) {
  int i = (blockIdx.x * 256 + threadIdx.x) * 4;
  const float* s; bf16* d;
  if (i < NW0) { s = s0; d = d0; }
  else if (i < NW0 + NW1) { s = s1; d = d1; i -= NW0; }
  else if (i < NW0 + 2 * NW1) { s = s2; d = d2; i -= NW0 + NW1; }
  else { s = s3; d = d3; i -= NW0 + 2 * NW1; }
  const float4 f = *(const float4*)(s + i);
  bf16x4 o; o.x = (bf16)f.x; o.y = (bf16)f.y; o.z = (bf16)f.z; o.w = (bf16)f.w;
  *(bf16x4*)(d + i) = o;
}

// ---------------- RoPE in-place on q and k (bf16) ----------------
__global__ __launch_bounds__(256) void rope_kernel(bf16* __restrict__ q, bf16* __restrict__ k,
                                                   const float* __restrict__ cosb,
                                                   const float* __restrict__ sinb) {
  const int tid = blockIdx.x * 256 + threadIdx.x;
  const int QN = 4096 * 8 * 128;
  const int KN = 4096 * 4 * 128;
  bf16* p; int row, d;
  if (tid < QN) {
    row = tid >> 10; const int rem = tid & 1023; d = rem & 127;
    p = q + (size_t)row * NQ + (rem >> 7) * 256 + d;
  } else {
    const int t2 = tid - QN; if (t2 >= KN) return;
    row = t2 >> 9; const int rem = t2 & 511; d = rem & 127;
    p = k + (size_t)row * NKV + (rem >> 7) * 256 + d;
  }
  const size_t cb = (size_t)row * 256 + d;
  const float c0 = cosb[cb], s0 = sinb[cb], c1 = cosb[cb + 128], s1 = sinb[cb + 128];
  const float a = (float)p[0], b = (float)p[128];
  p[0]   = (bf16)(a * c0 - b * s0);
  p[128] = (bf16)(b * c1 + a * s1);
}

// ======== 256x256 8-phase GEMM, m201-faithful double-barrier phases ========
// 512 threads = 8 waves (2M x 4N). BK=64. LDS: 2 x 64KB buffers of
// {A0,A1,B0,B1} 16KB halves. T2 XOR swizzle via pre-swizzled GLOBAL source.
// Phase = {reads+stage issued -> BAR -> lgkmcnt(0) -> 16 MFMA -> BAR}:
// reads drain while waves converge on BAR1; BAR2 guarantees all waves'
// phase-p reads complete before any phase-p+1 stage can clobber them.
//   P1: read bb23(t);           stage B1(t+1)->bufn;  G1 = a0 x bb01
//   P2: read a1(t);             stage B0(t+2)->bufs;  G2 = a0 x bb23
//   P3:                         stage A0(t+2)->bufs;  G3 = a1 x bb01
//   P4: VM4; read a0,bb01(t+1) from bufn; stage A1(t+2); G4 = a1 x bb23
// vmcnt queue at P4(t): {B0,A0,A1}(t+1)@P2-P4(t-1), B1(t+1)@P1(t),
// B0(t+2)@P2(t), A0(t+2)@P3(t) = 6 stages x 2 = 12 loads; drain to 4
// completes the oldest 4 stages = ALL of tile t+1 (incl. B1 for P1's bb23
// read). t==NT-2: queue is 8 loads -> VM0. Prologue: 14 loads -> VM6.
__device__ __forceinline__ void stage_half(const char* gbase, int stride, char* ldshalf, int tid) {
  const int c2 = ((tid & 7) * 16) ^ (((tid >> 3) & 7) << 4);  // pre-swizzled global col
#pragma unroll
  for (int q = 0; q < 2; ++q) {
    const int r = q * 64 + (tid >> 3);
    gld16(gbase + (size_t)r * stride + c2, ldshalf + q * 8192 + tid * 16);
  }
}

template<int MH, int NH, int KS>
__device__ __forceinline__ void mfma_burst(const bf16x8 (&af)[4][2], const bf16x8 (&bn)[2][2],
                                           f32x4 (&acc)[8][4]) {
  __builtin_amdgcn_s_setprio(1);
#pragma unroll
  for (int m = 0; m < 4; ++m)
#pragma unroll
    for (int n = 0; n < 2; ++n)
      acc[MH * 4 + m][NH * 2 + n] =
          __builtin_amdgcn_mfma_f32_16x16x32_bf16(af[m][KS], bn[n][KS], acc[MH * 4 + m][NH * 2 + n], 0, 0, 0);
  __builtin_amdgcn_s_setprio(0);
}

// MODE 0: fused QKV epilogue (N=4096: Q | K | V^T regions, 256-aligned).
// MODE 1: f32 out = acc + residual (direct store).
template<int NT, int NY, int MODE>
__global__ __launch_bounds__(512) void gemm8p(const bf16* __restrict__ A, const bf16* __restrict__ B,
                                              bf16* __restrict__ Cq, bf16* __restrict__ Ck,
                                              bf16* __restrict__ Cvt, float* __restrict__ fo,
                                              const float* __restrict__ resid, int Nd) {
  __shared__ char lds[131072];
  const int Ks = NT * 128;  // row stride in BYTES
  const char* Aby = (const char*)A;
  const char* Bby = (const char*)B;

  int wg = blockIdx.x;
  const int chunk = (int)gridDim.x >> 3;
  wg = (wg & 7) * chunk + (wg >> 3);              // XCD-bijective swizzle (grid%8==0)
  const int by = wg % NY, bx = wg / NY;
  const int m0 = bx * 256, n0 = by * 256;

  const int tid = threadIdx.x, lane = tid & 63, wv = tid >> 6;
  const int wm = wv >> 2, wn = wv & 3;
  const int r16 = lane & 15, g = lane >> 4;
  const int xr = (r16 & 7) << 4;
  const int cb0 = (g * 16) ^ xr, cb1 = (64 + g * 16) ^ xr;
  const int rdA = wm * 16384 + r16 * 128;
  const int rdB = 32768 + (wn >> 1) * 16384 + (wn & 1) * 8192 + r16 * 128;

  const char* A0g = Aby + (size_t)m0 * Ks;
  const char* A1g = Aby + (size_t)(m0 + 128) * Ks;
  const char* B0g = Bby + (size_t)n0 * Ks;
  const char* B1g = Bby + (size_t)(n0 + 128) * Ks;

  f32x4 acc[8][4] = {};
  bf16x8 a0[4][2], a1[4][2], bb01[2][2], bb23[2][2];

  auto read_a0bb01 = [&](const char* buf) {
#pragma unroll
    for (int n = 0; n < 2; ++n) bb01[n][0] = *(const bf16x8*)(buf + rdB + n * 2048 + cb0);
#pragma unroll
    for (int n = 0; n < 2; ++n) bb01[n][1] = *(const bf16x8*)(buf + rdB + n * 2048 + cb1);
#pragma unroll
    for (int m = 0; m < 4; ++m) a0[m][0] = *(const bf16x8*)(buf + rdA + m * 2048 + cb0);
#pragma unroll
    for (int m = 0; m < 4; ++m) a0[m][1] = *(const bf16x8*)(buf + rdA + m * 2048 + cb1);
  };

  // ---- prologue: tile0 {A0,A1,B0,B1} -> buf0; tile1 {B0,A0,A1} -> buf1 ----
  stage_half(A0g, Ks, lds + 0,     tid);
  stage_half(A1g, Ks, lds + 16384, tid);
  stage_half(B0g, Ks, lds + 32768, tid);
  stage_half(B1g, Ks, lds + 49152, tid);
  stage_half(B0g + 128, Ks, lds + 65536 + 32768, tid);
  stage_half(A0g + 128, Ks, lds + 65536 + 0,     tid);
  stage_half(A1g + 128, Ks, lds + 65536 + 16384, tid);
  VM6(); BAR();
  read_a0bb01(lds);  // tile 0

  for (int t = 0; t < NT; ++t) {
    const char* bufc = lds + (size_t)(t & 1) * 65536;
    char* bufn = lds + (size_t)((t + 1) & 1) * 65536;
    char* bufs = lds + (size_t)(t & 1) * 65536;  // tile t+2 shares parity with t
    // ---- P1: read bb23(t); stage B1(t+1)->bufn; G1 = a0 x bb01 ----
#pragma unroll
    for (int n = 0; n < 2; ++n) bb23[n][0] = *(const bf16x8*)(bufc + rdB + (2 + n) * 2048 + cb0);
#pragma unroll
    for (int n = 0; n < 2; ++n) bb23[n][1] = *(const bf16x8*)(bufc + rdB + (2 + n) * 2048 + cb1);
    if (t + 1 < NT)
      stage_half(B1g + (size_t)(t + 1) * 128, Ks, bufn + 49152, tid);
    BAR(); LGKM(0); SCHED0();
    mfma_burst<0, 0, 0>(a0, bb01, acc);
    mfma_burst<0, 0, 1>(a0, bb01, acc);
    SCHED0(); BAR();
    // ---- P2: read a1(t); stage B0(t+2); G2 = a0 x bb23 ----
#pragma unroll
    for (int m = 0; m < 4; ++m) a1[m][0] = *(const bf16x8*)(bufc + rdA + 8192 + m * 2048 + cb0);
#pragma unroll
    for (int m = 0; m < 4; ++m) a1[m][1] = *(const bf16x8*)(bufc + rdA + 8192 + m * 2048 + cb1);
    if (t + 2 < NT)
      stage_half(B0g + (size_t)(t + 2) * 128, Ks, bufs + 32768, tid);
    BAR(); LGKM(0); SCHED0();
    mfma_burst<0, 1, 0>(a0, bb23, acc);
    mfma_burst<0, 1, 1>(a0, bb23, acc);
    SCHED0(); BAR();
    // ---- P3: stage A0(t+2); G3 = a1 x bb01 ----
    if (t + 2 < NT)
      stage_half(A0g + (size_t)(t + 2) * 128, Ks, bufs + 0, tid);
    BAR(); SCHED0();
    mfma_burst<1, 0, 0>(a1, bb01, acc);
    mfma_burst<1, 0, 1>(a1, bb01, acc);
    SCHED0(); BAR();
    // ---- P4: VM4 confirms tile t+1; read-ahead a0,bb01(t+1); stage A1(t+2);
    //          G4 = a1 x bb23 ----
    if (t < NT - 2) { VM4(); } else if (t == NT - 2) { VM0(); }
    if (t + 1 < NT) read_a0bb01(bufn);
    if (t + 2 < NT)
      stage_half(A1g + (size_t)(t + 2) * 128, Ks, bufs + 16384, tid);
    BAR(); LGKM(0); SCHED0();
    mfma_burst<1, 1, 0>(a1, bb23, acc);
    mfma_burst<1, 1, 1>(a1, bb23, acc);
    SCHED0(); BAR();
  }

  // ---- epilogue ----
  const int mrow = m0 + wm * 128 + g * 4;
  const int ncol = n0 + wn * 64 + r16;
#pragma unroll
  for (int i = 0; i < 8; ++i)
#pragma unroll
    for (int j = 0; j < 4; ++j)
#pragma unroll
      for (int e = 0; e < 4; ++e) {
        const int m = mrow + i * 16 + e;
        const int n = ncol + j * 16;
        const float vv = acc[i][j][e];
        if constexpr (MODE == 0) {
          if (n0 < 2048) {
            Cq[(size_t)m * 2048 + n] = (bf16)vv;
          } else if (n0 < 3072) {
            Ck[(size_t)m * 1024 + (n - 2048)] = (bf16)vv;
          } else {
            const int b2 = m >> 11, s = m & 2047;
            Cvt[((size_t)b2 * 1024 + (n - 3072)) * SEQ + s] = (bf16)vv;
          }
        } else {
          fo[(size_t)m * Nd + n] = vv + resid[(size_t)m * Nd + n];
        }
      }
}

// ---------------- attention tile loads (K 32x256, V^T 256x32) ----------------
__device__ __forceinline__ void attn_load(const bf16* __restrict__ kgp, const bf16* __restrict__ vgp,
                                          int j0, int t, bf16x8* kr, bf16x8* vr) {
#pragma unroll
  for (int it = 0; it < 4; ++it) {
    const int flat = it * 2048 + t * 8;
    kr[it] = *(const bf16x8*)&kgp[(size_t)((flat >> 8) + j0) * NKV + (flat & 255)];
    vr[it] = *(const bf16x8*)&vgp[(size_t)(flat >> 5) * SEQ + j0 + (flat & 31)];
  }
}

// ---------------- Flash attention: QT=64 (4 waves x 16 rows), KT=32 --------
__global__ __launch_bounds__(256) void attn_kernel(const bf16* __restrict__ q, const bf16* __restrict__ k,
                                                   const bf16* __restrict__ vt, bf16* __restrict__ ao) {
  __shared__ bf16 smem[21248];
  bf16* const qs  = smem;
  bf16* const ksl = smem;
  bf16* const vtl = smem + 8448;
  bf16* const pl  = smem + 18688;
  int qt = blockIdx.x;
  const int h = blockIdx.y, b = blockIdx.z;
  if (b) qt = 31 - qt;
  const int kvh = h >> 1;
  const int t = threadIdx.x, lane = t & 63, w = t >> 6;
  const int r16 = lane & 15, g = lane >> 4;
  const int i_base = qt * 64;

  {
    const bf16* qg = q + ((size_t)(b * SEQ + i_base)) * NQ + h * 256;
#pragma unroll
    for (int it = 0; it < 8; ++it) {
      const int flat = it * 2048 + t * 8;
      const int row = flat >> 8, dd = flat & 255;
      *(bf16x8*)&qs[row * 264 + dd] = *(const bf16x8*)&qg[(size_t)row * NQ + dd];
    }
  }
  __syncthreads();
  bf16x8 aq[8];
#pragma unroll
  for (int c = 0; c < 8; ++c) aq[c] = *(const bf16x8*)&qs[(w * 16 + r16) * 264 + c * 32 + g * 8];

  f32x4 oacc[16] = {};
  float lrun[4] = {0.f, 0.f, 0.f, 0.f};
  int jb = i_base - 1023; if (jb < 0) jb = 0; jb &= ~31;
  const int je = i_base + 63;
  const bf16* kg = k + (size_t)b * SEQ * NKV + kvh * 256;
  const bf16* vg = vt + ((size_t)b * NKV + kvh * 256) * SEQ;

  bf16x8 kr[4], vr[4];
  attn_load(kg, vg, jb, t, kr, vr);

  for (int j0 = jb; j0 <= je; j0 += 32) {
    __syncthreads();
#pragma unroll
    for (int it = 0; it < 4; ++it) {
      const int flat = it * 2048 + t * 8;
      *(bf16x8*)&ksl[(flat >> 8) * 264 + (flat & 255)] = kr[it];
      *(bf16x8*)&vtl[(flat >> 5) * 40 + (flat & 31)] = vr[it];
    }
    __syncthreads();
    const int jn = (j0 + 32 <= je) ? (j0 + 32) : j0;
    attn_load(kg, vg, jn, t, kr, vr);

    f32x4 sc0 = {}, sc1 = {};
#pragma unroll
    for (int c = 0; c < 8; ++c) {
      const bf16x8 b0 = *(const bf16x8*)&ksl[r16 * 264 + c * 32 + g * 8];
      const bf16x8 b1 = *(const bf16x8*)&ksl[(16 + r16) * 264 + c * 32 + g * 8];
      sc0 = __builtin_amdgcn_mfma_f32_16x16x32_bf16(aq[c], b0, sc0, 0, 0, 0);
      sc1 = __builtin_amdgcn_mfma_f32_16x16x32_bf16(aq[c], b1, sc1, 0, 0, 0);
    }
    const bool full = (j0 + 31 <= i_base) && (i_base + 63 - j0 < 1024);
#pragma unroll
    for (int e = 0; e < 4; ++e) {
      const float t0 = __expf(sc0[e] * 0.0025f);
      const float t1 = __expf(sc1[e] * 0.0025f);
      float p0 = __expf(-100.0f / (t0 + 1.0f));
      float p1 = __expf(-100.0f / (t1 + 1.0f));
      if (!full) {
        const int irow = i_base + w * 16 + g * 4 + e;
        const int jg0 = j0 + r16, jg1 = j0 + 16 + r16;
        if (jg0 > irow || irow - jg0 >= 1024) p0 = 0.f;
        if (jg1 > irow || irow - jg1 >= 1024) p1 = 0.f;
      }
      const bf16 b0 = (bf16)p0, b1 = (bf16)p1;
      lrun[e] += (float)b0 + (float)b1;
      pl[w * 640 + (g * 4 + e) * 40 + r16] = b0;
      pl[w * 640 + (g * 4 + e) * 40 + 16 + r16] = b1;
    }
    const bf16x8 pa = *(const bf16x8*)&pl[w * 640 + r16 * 40 + g * 8];
#pragma unroll
    for (int nf = 0; nf < 16; ++nf) {
      const bf16x8 vb = *(const bf16x8*)&vtl[(nf * 16 + r16) * 40 + g * 8];
      oacc[nf] = __builtin_amdgcn_mfma_f32_16x16x32_bf16(pa, vb, oacc[nf], 0, 0, 0);
    }
  }
  float inv[4];
#pragma unroll
  for (int e = 0; e < 4; ++e) {
#pragma unroll
    for (int o = 1; o < 16; o <<= 1) lrun[e] += __shfl_xor(lrun[e], o, 64);
    inv[e] = 1.0f / lrun[e];
  }
  bf16* aor = ao + ((size_t)(b * SEQ + i_base + w * 16)) * NQ + h * 256;
#pragma unroll
  for (int nf = 0; nf < 16; ++nf)
#pragma unroll
    for (int e = 0; e < 4; ++e)
      aor[(size_t)(g * 4 + e) * NQ + nf * 16 + r16] = (bf16)(oacc[nf][e] * inv[e]);
}

extern "C" void kernel_launch(void* const* d_in, const int* in_sizes, int n_in,
                              void* d_out, int out_size, void* d_ws, size_t ws_size,
                              hipStream_t stream) {
  const float* hs   = (const float*)d_in[0];
  const float* cosb = (const float*)d_in[1];
  const float* sinb = (const float*)d_in[2];
  const float* rw   = (const float*)d_in[3];
  const float* Wq   = (const float*)d_in[4];
  const float* Wk   = (const float*)d_in[5];
  const float* Wv   = (const float*)d_in[6];
  const float* Wo   = (const float*)d_in[7];
  float* out = (float*)d_out;
  char* ws = (char*)d_ws;

  bf16* xb   = (bf16*)(ws);             // 4096x2304
  bf16* wqkv = (bf16*)(ws + 18874368);  // [4096][2304]: Wq(2048) | Wk(1024) | Wv(1024)
  bf16* wkb  = wqkv + (size_t)2048 * 2304;
  bf16* wvb  = wqkv + (size_t)3072 * 2304;
  bf16* wob  = (bf16*)(ws + 37748736);  // 2304x2048
  bf16* qg   = (bf16*)(ws + 47185920);  // 4096x2048
  bf16* kg   = (bf16*)(ws + 63963136);  // 4096x1024
  bf16* vtg  = (bf16*)(ws + 72351744);  // [2][1024][2048]
  bf16* ag   = (bf16*)(ws + 80740352);  // 4096x2048

  rmsnorm_kernel<<<4096, 256, 0, stream>>>(hs, rw, xb);
  cvt4_kernel<<<(NW0 + 2 * NW1 + NW3) / 4 / 256, 256, 0, stream>>>(Wq, Wk, Wv, Wo, wqkv, wkb, wvb, wob);
  // QKV: M=4096, N=4096, K=2304 (NT=36), grid 16x16=256
  gemm8p<36, 16, 0><<<256, 512, 0, stream>>>(xb, wqkv, qg, kg, vtg, nullptr, nullptr, 4096);
  rope_kernel<<<(4096 * 8 * 128 + 4096 * 4 * 128) / 256, 256, 0, stream>>>(qg, kg, cosb, sinb);
  attn_kernel<<<dim3(32, 8, 2), 256, 0, stream>>>(qg, kg, vtg, ag);
  // O-proj: M=4096, N=2304, K=2048 (NT=32), grid 16x9=144, direct f32+resid
  gemm8p<32, 9, 1><<<144, 512, 0, stream>>>(ag, wob, nullptr, nullptr, nullptr, out, hs, 2304);
}

// Round 12
// 248.278 us; speedup vs baseline: 1.1412x; 1.0558x over previous
//
#include <hip/hip_runtime.h>
#include <cstdint>

typedef __bf16 bf16;
typedef __bf16 bf16x8 __attribute__((ext_vector_type(8)));
typedef __bf16 bf16x4 __attribute__((ext_vector_type(4)));
typedef float  f32x4  __attribute__((ext_vector_type(4)));

#define HIDDEN 2304
#define NQ 2048
#define NKV 1024
#define SEQ 2048

typedef __attribute__((address_space(1))) void gv_t;
typedef __attribute__((address_space(3))) void lv_t;
__device__ __forceinline__ void gld16(const void* g, void* l) {
  __builtin_amdgcn_global_load_lds((gv_t*)g, (lv_t*)l, 16, 0, 0);
}

#define BAR()    asm volatile("s_barrier" ::: "memory")
#define LGKM(n)  asm volatile("s_waitcnt lgkmcnt(" #n ")" ::: "memory")
#define VM6()    asm volatile("s_waitcnt vmcnt(6)" ::: "memory")
#define VM2()    asm volatile("s_waitcnt vmcnt(2)" ::: "memory")
#define VM0()    asm volatile("s_waitcnt vmcnt(0)" ::: "memory")
#define SCHED0() __builtin_amdgcn_sched_barrier(0)

// ---------------- RMSNorm + bf16 cast ----------------
__global__ __launch_bounds__(256) void rmsnorm_kernel(const float* __restrict__ x,
                                                      const float* __restrict__ w,
                                                      bf16* __restrict__ xb) {
  const int row = blockIdx.x, t = threadIdx.x;
  const float* xr = x + (size_t)row * HIDDEN;
  float v[9]; float ss = 0.f;
#pragma unroll
  for (int i = 0; i < 9; ++i) { v[i] = xr[t + i * 256]; ss += v[i] * v[i]; }
#pragma unroll
  for (int o = 32; o; o >>= 1) ss += __shfl_xor(ss, o, 64);
  __shared__ float wss[4];
  if ((t & 63) == 0) wss[t >> 6] = ss;
  __syncthreads();
  ss = wss[0] + wss[1] + wss[2] + wss[3];
  const float rs = rsqrtf(ss * (1.0f / HIDDEN) + 1e-6f);
  bf16* xo = xb + (size_t)row * HIDDEN;
#pragma unroll
  for (int i = 0; i < 9; ++i) xo[t + i * 256] = (bf16)(v[i] * rs * (1.0f + w[t + i * 256]));
}

// ---------------- fused f32 -> bf16 weight convert ----------
// Wq, Wk rows are PERMUTED for fused RoPE: head-dim d -> interleaved col
// perm(d) = ((d&127)<<1)|(d>>7), so pair (d, d+128) sits in adjacent cols
// (= adjacent lanes of the MFMA C-fragment). Wv, Wo linear.
#define NW0 (2048 * 2304)
#define NW1 (1024 * 2304)
#define NW3 (2304 * 2048)
__global__ __launch_bounds__(256) void cvt4_kernel(const float* __restrict__ s0, const float* __restrict__ s1,
                                                   const float* __restrict__ s2, const float* __restrict__ s3,
                                                   bf16* __restrict__ d0, bf16* __restrict__ d1,
                                                   bf16* __restrict__ d2, bf16* __restrict__ d3) {
  int i = (blockIdx.x * 256 + threadIdx.x) * 4;
  const float* s; bf16* dst; size_t oidx;
  if (i < NW0) {
    s = s0; const int r = i / 2304, c = i % 2304, d = r & 255;
    oidx = (size_t)((r & ~255) | ((d & 127) << 1) | (d >> 7)) * 2304 + c; dst = d0;
  } else if (i < NW0 + NW1) {
    i -= NW0;
    s = s1; const int r = i / 2304, c = i % 2304, d = r & 255;
    oidx = (size_t)((r & ~255) | ((d & 127) << 1) | (d >> 7)) * 2304 + c; dst = d1;
  } else if (i < NW0 + 2 * NW1) {
    i -= NW0 + NW1; s = s2; oidx = i; dst = d2;
  } else {
    i -= NW0 + 2 * NW1; s = s3; oidx = i; dst = d3;
  }
  const float4 f = *(const float4*)(s + i);
  bf16x4 o; o.x = (bf16)f.x; o.y = (bf16)f.y; o.z = (bf16)f.z; o.w = (bf16)f.w;
  *(bf16x4*)(dst + oidx) = o;
}

// ======== 256x256 8-phase GEMM (r8 engine) with fused-RoPE epilogue ========
__device__ __forceinline__ void stage_half(const char* gbase, int stride, char* ldshalf, int tid) {
  const int c2 = ((tid & 7) * 16) ^ (((tid >> 3) & 7) << 4);  // pre-swizzled global col
#pragma unroll
  for (int q = 0; q < 2; ++q) {
    const int r = q * 64 + (tid >> 3);
    gld16(gbase + (size_t)r * stride + c2, ldshalf + q * 8192 + tid * 16);
  }
}

template<int MH, int NH, int KS>
__device__ __forceinline__ void mfma_burst(const bf16x8 (&af)[4][2], const bf16x8 (&bn)[2][2],
                                           f32x4 (&acc)[8][4]) {
  __builtin_amdgcn_s_setprio(1);
#pragma unroll
  for (int m = 0; m < 4; ++m)
#pragma unroll
    for (int n = 0; n < 2; ++n)
      acc[MH * 4 + m][NH * 2 + n] =
          __builtin_amdgcn_mfma_f32_16x16x32_bf16(af[m][KS], bn[n][KS], acc[MH * 4 + m][NH * 2 + n], 0, 0, 0);
  __builtin_amdgcn_s_setprio(0);
}

// MODE 0: fused QKV epilogue. N=4096 tiles: n0<2048 Q (RoPE+deperm),
//         n0 in [2048,3072) K (RoPE+deperm), n0>=3072 V^T.
// MODE 1: f32 out = acc + residual (direct store).
template<int NT, int NY, int MODE>
__global__ __launch_bounds__(512) void gemm8p(const bf16* __restrict__ A, const bf16* __restrict__ B,
                                              bf16* __restrict__ Cq, bf16* __restrict__ Ck,
                                              bf16* __restrict__ Cvt, float* __restrict__ fo,
                                              const float* __restrict__ resid, int Nd,
                                              const float* __restrict__ cosb,
                                              const float* __restrict__ sinb) {
  __shared__ char lds[131072];
  const int Ks = NT * 128;  // row stride in BYTES
  const char* Aby = (const char*)A;
  const char* Bby = (const char*)B;

  int wg = blockIdx.x;
  const int chunk = (int)gridDim.x >> 3;
  wg = (wg & 7) * chunk + (wg >> 3);              // XCD-bijective swizzle (grid%8==0)
  const int by = wg % NY, bx = wg / NY;
  const int m0 = bx * 256, n0 = by * 256;

  const int tid = threadIdx.x, lane = tid & 63, wv = tid >> 6;
  const int wm = wv >> 2, wn = wv & 3;
  const int r16 = lane & 15, g = lane >> 4;
  const int xr = (r16 & 7) << 4;
  const int cb0 = (g * 16) ^ xr, cb1 = (64 + g * 16) ^ xr;
  const int rdA = wm * 16384 + r16 * 128;
  const int rdB = 32768 + (wn >> 1) * 16384 + (wn & 1) * 8192 + r16 * 128;

  const char* A0g = Aby + (size_t)m0 * Ks;
  const char* A1g = Aby + (size_t)(m0 + 128) * Ks;
  const char* B0g = Bby + (size_t)n0 * Ks;
  const char* B1g = Bby + (size_t)(n0 + 128) * Ks;

  f32x4 acc[8][4] = {};
  bf16x8 a0[4][2], a1[4][2], bb01[2][2], bb23[2][2];

  auto read_a0bb01 = [&](const char* buf) {
#pragma unroll
    for (int n = 0; n < 2; ++n) bb01[n][0] = *(const bf16x8*)(buf + rdB + n * 2048 + cb0);
#pragma unroll
    for (int n = 0; n < 2; ++n) bb01[n][1] = *(const bf16x8*)(buf + rdB + n * 2048 + cb1);
#pragma unroll
    for (int m = 0; m < 4; ++m) a0[m][0] = *(const bf16x8*)(buf + rdA + m * 2048 + cb0);
#pragma unroll
    for (int m = 0; m < 4; ++m) a0[m][1] = *(const bf16x8*)(buf + rdA + m * 2048 + cb1);
  };

  // ---- prologue: tile0 {A0,A1,B0,B1} -> buf0; tile1 {B0,A0,A1} -> buf1 ----
  stage_half(A0g, Ks, lds + 0,     tid);
  stage_half(A1g, Ks, lds + 16384, tid);
  stage_half(B0g, Ks, lds + 32768, tid);
  stage_half(B1g, Ks, lds + 49152, tid);
  stage_half(B0g + 128, Ks, lds + 65536 + 32768, tid);
  stage_half(A0g + 128, Ks, lds + 65536 + 0,     tid);
  stage_half(A1g + 128, Ks, lds + 65536 + 16384, tid);
  VM6(); BAR();
  read_a0bb01(lds);  // tile 0

  for (int t = 0; t < NT; ++t) {
    const char* bufc = lds + (size_t)(t & 1) * 65536;
    char* bufn = lds + (size_t)((t + 1) & 1) * 65536;
    char* bufs = lds + (size_t)(t & 1) * 65536;
    // ---- P1: a0/bb01 ready; issue bb23 then a1; G1 ----
    LGKM(0);
#pragma unroll
    for (int n = 0; n < 2; ++n) bb23[n][0] = *(const bf16x8*)(bufc + rdB + (2 + n) * 2048 + cb0);
#pragma unroll
    for (int n = 0; n < 2; ++n) bb23[n][1] = *(const bf16x8*)(bufc + rdB + (2 + n) * 2048 + cb1);
#pragma unroll
    for (int m = 0; m < 4; ++m) a1[m][0] = *(const bf16x8*)(bufc + rdA + 8192 + m * 2048 + cb0);
#pragma unroll
    for (int m = 0; m < 4; ++m) a1[m][1] = *(const bf16x8*)(bufc + rdA + 8192 + m * 2048 + cb1);
    SCHED0();
    mfma_burst<0, 0, 0>(a0, bb01, acc);
    mfma_burst<0, 0, 1>(a0, bb01, acc);
    SCHED0(); BAR();
    // ---- P2: bb23 ready; stage B1(t+1); G2 ----
    LGKM(8);
    if (t + 1 < NT)
      stage_half(B1g + (size_t)(t + 1) * 128, Ks, bufn + 49152, tid);
    SCHED0();
    mfma_burst<0, 1, 0>(a0, bb23, acc);
    mfma_burst<0, 1, 1>(a0, bb23, acc);
    SCHED0(); BAR();
    // ---- P3: a1 ready; stage B0(t+2); G3 ----
    LGKM(0);
    if (t + 2 < NT)
      stage_half(B0g + (size_t)(t + 2) * 128, Ks, bufs + 32768, tid);
    SCHED0();
    mfma_burst<1, 0, 0>(a1, bb01, acc);
    mfma_burst<1, 0, 1>(a1, bb01, acc);
    SCHED0(); BAR();
    // ---- P4: counted vmcnt confirms tile t+1; stage A0,A1(t+2); G4 ----
    if (t < NT - 2) { VM2(); } else if (t == NT - 2) { VM0(); }
    if (t + 2 < NT) {
      stage_half(A0g + (size_t)(t + 2) * 128, Ks, bufs + 0,     tid);
      stage_half(A1g + (size_t)(t + 2) * 128, Ks, bufs + 16384, tid);
    }
    SCHED0();
    mfma_burst<1, 1, 0>(a1, bb23, acc);
    mfma_burst<1, 1, 1>(a1, bb23, acc);
    SCHED0(); BAR();
    if (t + 1 < NT) read_a0bb01(bufn);  // read-ahead for next tile
  }

  // ---- epilogue (MODE 0: fused RoPE for Q/K regions) ----
  const int mrow = m0 + wm * 128 + g * 4;
  const int ncol = n0 + wn * 64 + r16;
#pragma unroll
  for (int i = 0; i < 8; ++i)
#pragma unroll
    for (int j = 0; j < 4; ++j)
#pragma unroll
      for (int e = 0; e < 4; ++e) {
        const int m = mrow + i * 16 + e;
        const int n = ncol + j * 16;
        float v = acc[i][j][e];
        if constexpr (MODE == 0) {
          if (n0 < 3072) {
            // RoPE: partner (d, d+128) is the adjacent column (lane r16^1).
            const float p = __shfl_xor(v, 1);
            const int jj = n & 255;
            const int f = jj >> 1;
            const float c  = cosb[(size_t)m * 256 + f];
            const float sn = sinb[(size_t)m * 256 + f];
            v = (jj & 1) ? (v * c + p * sn) : (v * c - p * sn);
            const int d = f + ((jj & 1) << 7);  // de-permute
            if (n0 < 2048) {
              Cq[(size_t)m * 2048 + (n & ~255) + d] = (bf16)v;
            } else {
              Ck[(size_t)m * 1024 + ((n - 2048) & ~255) + d] = (bf16)v;
            }
          } else {
            const int b2 = m >> 11, s = m & 2047;
            Cvt[((size_t)b2 * 1024 + (n - 3072)) * SEQ + s] = (bf16)v;
          }
        } else {
          fo[(size_t)m * Nd + n] = v + resid[(size_t)m * Nd + n];
        }
      }
}

// ---------------- attention tile loads (K 32x256, V^T 256x32) ----------------
__device__ __forceinline__ void attn_load(const bf16* __restrict__ kgp, const bf16* __restrict__ vgp,
                                          int j0, int t, bf16x8* kr, bf16x8* vr) {
#pragma unroll
  for (int it = 0; it < 4; ++it) {
    const int flat = it * 2048 + t * 8;
    kr[it] = *(const bf16x8*)&kgp[(size_t)((flat >> 8) + j0) * NKV + (flat & 255)];
    vr[it] = *(const bf16x8*)&vgp[(size_t)(flat >> 5) * SEQ + j0 + (flat & 31)];
  }
}

// ---------------- Flash attention: QT=64 (4 waves x 16 rows), KT=32 --------
__global__ __launch_bounds__(256) void attn_kernel(const bf16* __restrict__ q, const bf16* __restrict__ k,
                                                   const bf16* __restrict__ vt, bf16* __restrict__ ao) {
  __shared__ bf16 smem[21248];
  bf16* const qs  = smem;
  bf16* const ksl = smem;
  bf16* const vtl = smem + 8448;
  bf16* const pl  = smem + 18688;
  int qt = blockIdx.x;
  const int h = blockIdx.y, b = blockIdx.z;
  if (b) qt = 31 - qt;
  const int kvh = h >> 1;
  const int t = threadIdx.x, lane = t & 63, w = t >> 6;
  const int r16 = lane & 15, g = lane >> 4;
  const int i_base = qt * 64;

  {
    const bf16* qg = q + ((size_t)(b * SEQ + i_base)) * NQ + h * 256;
#pragma unroll
    for (int it = 0; it < 8; ++it) {
      const int flat = it * 2048 + t * 8;
      const int row = flat >> 8, dd = flat & 255;
      *(bf16x8*)&qs[row * 264 + dd] = *(const bf16x8*)&qg[(size_t)row * NQ + dd];
    }
  }
  __syncthreads();
  bf16x8 aq[8];
#pragma unroll
  for (int c = 0; c < 8; ++c) aq[c] = *(const bf16x8*)&qs[(w * 16 + r16) * 264 + c * 32 + g * 8];

  f32x4 oacc[16] = {};
  float lrun[4] = {0.f, 0.f, 0.f, 0.f};
  int jb = i_base - 1023; if (jb < 0) jb = 0; jb &= ~31;
  const int je = i_base + 63;
  const bf16* kg = k + (size_t)b * SEQ * NKV + kvh * 256;
  const bf16* vg = vt + ((size_t)b * NKV + kvh * 256) * SEQ;

  bf16x8 kr[4], vr[4];
  attn_load(kg, vg, jb, t, kr, vr);

  for (int j0 = jb; j0 <= je; j0 += 32) {
    __syncthreads();
#pragma unroll
    for (int it = 0; it < 4; ++it) {
      const int flat = it * 2048 + t * 8;
      *(bf16x8*)&ksl[(flat >> 8) * 264 + (flat & 255)] = kr[it];
      *(bf16x8*)&vtl[(flat >> 5) * 40 + (flat & 31)] = vr[it];
    }
    __syncthreads();
    const int jn = (j0 + 32 <= je) ? (j0 + 32) : j0;
    attn_load(kg, vg, jn, t, kr, vr);

    f32x4 sc0 = {}, sc1 = {};
#pragma unroll
    for (int c = 0; c < 8; ++c) {
      const bf16x8 b0 = *(const bf16x8*)&ksl[r16 * 264 + c * 32 + g * 8];
      const bf16x8 b1 = *(const bf16x8*)&ksl[(16 + r16) * 264 + c * 32 + g * 8];
      sc0 = __builtin_amdgcn_mfma_f32_16x16x32_bf16(aq[c], b0, sc0, 0, 0, 0);
      sc1 = __builtin_amdgcn_mfma_f32_16x16x32_bf16(aq[c], b1, sc1, 0, 0, 0);
    }
    const bool full = (j0 + 31 <= i_base) && (i_base + 63 - j0 < 1024);
#pragma unroll
    for (int e = 0; e < 4; ++e) {
      const float t0 = __expf(sc0[e] * 0.0025f);
      const float t1 = __expf(sc1[e] * 0.0025f);
      float p0 = __expf(-100.0f / (t0 + 1.0f));
      float p1 = __expf(-100.0f / (t1 + 1.0f));
      if (!full) {
        const int irow = i_base + w * 16 + g * 4 + e;
        const int jg0 = j0 + r16, jg1 = j0 + 16 + r16;
        if (jg0 > irow || irow - jg0 >= 1024) p0 = 0.f;
        if (jg1 > irow || irow - jg1 >= 1024) p1 = 0.f;
      }
      const bf16 b0 = (bf16)p0, b1 = (bf16)p1;
      lrun[e] += (float)b0 + (float)b1;
      pl[w * 640 + (g * 4 + e) * 40 + r16] = b0;
      pl[w * 640 + (g * 4 + e) * 40 + 16 + r16] = b1;
    }
    const bf16x8 pa = *(const bf16x8*)&pl[w * 640 + r16 * 40 + g * 8];
#pragma unroll
    for (int nf = 0; nf < 16; ++nf) {
      const bf16x8 vb = *(const bf16x8*)&vtl[(nf * 16 + r16) * 40 + g * 8];
      oacc[nf] = __builtin_amdgcn_mfma_f32_16x16x32_bf16(pa, vb, oacc[nf], 0, 0, 0);
    }
  }
  float inv[4];
#pragma unroll
  for (int e = 0; e < 4; ++e) {
#pragma unroll
    for (int o = 1; o < 16; o <<= 1) lrun[e] += __shfl_xor(lrun[e], o, 64);
    inv[e] = 1.0f / lrun[e];
  }
  bf16* aor = ao + ((size_t)(b * SEQ + i_base + w * 16)) * NQ + h * 256;
#pragma unroll
  for (int nf = 0; nf < 16; ++nf)
#pragma unroll
    for (int e = 0; e < 4; ++e)
      aor[(size_t)(g * 4 + e) * NQ + nf * 16 + r16] = (bf16)(oacc[nf][e] * inv[e]);
}

extern "C" void kernel_launch(void* const* d_in, const int* in_sizes, int n_in,
                              void* d_out, int out_size, void* d_ws, size_t ws_size,
                              hipStream_t stream) {
  const float* hs   = (const float*)d_in[0];
  const float* cosb = (const float*)d_in[1];
  const float* sinb = (const float*)d_in[2];
  const float* rw   = (const float*)d_in[3];
  const float* Wq   = (const float*)d_in[4];
  const float* Wk   = (const float*)d_in[5];
  const float* Wv   = (const float*)d_in[6];
  const float* Wo   = (const float*)d_in[7];
  float* out = (float*)d_out;
  char* ws = (char*)d_ws;

  bf16* xb   = (bf16*)(ws);             // 4096x2304
  bf16* wqkv = (bf16*)(ws + 18874368);  // [4096][2304]: Wq(2048) | Wk(1024) | Wv(1024)
  bf16* wkb  = wqkv + (size_t)2048 * 2304;
  bf16* wvb  = wqkv + (size_t)3072 * 2304;
  bf16* wob  = (bf16*)(ws + 37748736);  // 2304x2048
  bf16* qg   = (bf16*)(ws + 47185920);  // 4096x2048
  bf16* kg   = (bf16*)(ws + 63963136);  // 4096x1024
  bf16* vtg  = (bf16*)(ws + 72351744);  // [2][1024][2048]
  bf16* ag   = (bf16*)(ws + 80740352);  // 4096x2048

  rmsnorm_kernel<<<4096, 256, 0, stream>>>(hs, rw, xb);
  cvt4_kernel<<<(NW0 + 2 * NW1 + NW3) / 4 / 256, 256, 0, stream>>>(Wq, Wk, Wv, Wo, wqkv, wkb, wvb, wob);
  // QKV: M=4096, N=4096, K=2304 (NT=36), grid 16x16=256, fused RoPE epilogue
  gemm8p<36, 16, 0><<<256, 512, 0, stream>>>(xb, wqkv, qg, kg, vtg, nullptr, nullptr, 4096, cosb, sinb);
  attn_kernel<<<dim3(32, 8, 2), 256, 0, stream>>>(qg, kg, vtg, ag);
  // O-proj: M=4096, N=2304, K=2048 (NT=32), grid 16x9=144, direct f32+resid
  gemm8p<32, 9, 1><<<144, 512, 0, stream>>>(ag, wob, nullptr, nullptr, nullptr, out, hs, 2304, nullptr, nullptr);
}

// Round 13
// 238.736 us; speedup vs baseline: 1.1868x; 1.0400x over previous
//
#include <hip/hip_runtime.h>
#include <cstdint>

typedef __bf16 bf16;
typedef __bf16 bf16x8 __attribute__((ext_vector_type(8)));
typedef __bf16 bf16x4 __attribute__((ext_vector_type(4)));
typedef float  f32x4  __attribute__((ext_vector_type(4)));

#define HIDDEN 2304
#define NQ 2048
#define NKV 1024
#define SEQ 2048

typedef __attribute__((address_space(1))) void gv_t;
typedef __attribute__((address_space(3))) void lv_t;
__device__ __forceinline__ void gld16(const void* g, void* l) {
  __builtin_amdgcn_global_load_lds((gv_t*)g, (lv_t*)l, 16, 0, 0);
}

#define BAR()    asm volatile("s_barrier" ::: "memory")
#define LGKM(n)  asm volatile("s_waitcnt lgkmcnt(" #n ")" ::: "memory")
#define VM6()    asm volatile("s_waitcnt vmcnt(6)" ::: "memory")
#define VM2()    asm volatile("s_waitcnt vmcnt(2)" ::: "memory")
#define VM0()    asm volatile("s_waitcnt vmcnt(0)" ::: "memory")
#define SCHED0() __builtin_amdgcn_sched_barrier(0)

// ---------------- RMSNorm + bf16 cast ----------------
__global__ __launch_bounds__(256) void rmsnorm_kernel(const float* __restrict__ x,
                                                      const float* __restrict__ w,
                                                      bf16* __restrict__ xb) {
  const int row = blockIdx.x, t = threadIdx.x;
  const float* xr = x + (size_t)row * HIDDEN;
  float v[9]; float ss = 0.f;
#pragma unroll
  for (int i = 0; i < 9; ++i) { v[i] = xr[t + i * 256]; ss += v[i] * v[i]; }
#pragma unroll
  for (int o = 32; o; o >>= 1) ss += __shfl_xor(ss, o, 64);
  __shared__ float wss[4];
  if ((t & 63) == 0) wss[t >> 6] = ss;
  __syncthreads();
  ss = wss[0] + wss[1] + wss[2] + wss[3];
  const float rs = rsqrtf(ss * (1.0f / HIDDEN) + 1e-6f);
  bf16* xo = xb + (size_t)row * HIDDEN;
#pragma unroll
  for (int i = 0; i < 9; ++i) xo[t + i * 256] = (bf16)(v[i] * rs * (1.0f + w[t + i * 256]));
}

// ---------------- fused f32 -> bf16 weight convert ----------
// Wq, Wk rows PERMUTED for fused RoPE with SAME-LANE pairing:
// head-dim d -> col(d) = ((d>>4)&7)<<5 | (d>>7)<<4 | (d&15).
// Pair (d, d+128) lands at cols (c, c+16): same lane, adjacent j-fragment.
#define NW0 (2048 * 2304)
#define NW1 (1024 * 2304)
#define NW3 (2304 * 2048)
__global__ __launch_bounds__(256) void cvt4_kernel(const float* __restrict__ s0, const float* __restrict__ s1,
                                                   const float* __restrict__ s2, const float* __restrict__ s3,
                                                   bf16* __restrict__ d0, bf16* __restrict__ d1,
                                                   bf16* __restrict__ d2, bf16* __restrict__ d3) {
  int i = (blockIdx.x * 256 + threadIdx.x) * 4;
  const float* s; bf16* dst; size_t oidx;
  if (i < NW0) {
    s = s0; const int r = i / 2304, c = i % 2304, d = r & 255;
    const int col = (((d >> 4) & 7) << 5) | ((d >> 7) << 4) | (d & 15);
    oidx = (size_t)((r & ~255) | col) * 2304 + c; dst = d0;
  } else if (i < NW0 + NW1) {
    i -= NW0;
    s = s1; const int r = i / 2304, c = i % 2304, d = r & 255;
    const int col = (((d >> 4) & 7) << 5) | ((d >> 7) << 4) | (d & 15);
    oidx = (size_t)((r & ~255) | col) * 2304 + c; dst = d1;
  } else if (i < NW0 + 2 * NW1) {
    i -= NW0 + NW1; s = s2; oidx = i; dst = d2;
  } else {
    i -= NW0 + 2 * NW1; s = s3; oidx = i; dst = d3;
  }
  const float4 f = *(const float4*)(s + i);
  bf16x4 o; o.x = (bf16)f.x; o.y = (bf16)f.y; o.z = (bf16)f.z; o.w = (bf16)f.w;
  *(bf16x4*)(dst + oidx) = o;
}

// ======== 256x256 8-phase GEMM (r8 engine) with fused-RoPE epilogue ========
__device__ __forceinline__ void stage_half(const char* gbase, int stride, char* ldshalf, int tid) {
  const int c2 = ((tid & 7) * 16) ^ (((tid >> 3) & 7) << 4);  // pre-swizzled global col
#pragma unroll
  for (int q = 0; q < 2; ++q) {
    const int r = q * 64 + (tid >> 3);
    gld16(gbase + (size_t)r * stride + c2, ldshalf + q * 8192 + tid * 16);
  }
}

template<int MH, int NH, int KS>
__device__ __forceinline__ void mfma_burst(const bf16x8 (&af)[4][2], const bf16x8 (&bn)[2][2],
                                           f32x4 (&acc)[8][4]) {
  __builtin_amdgcn_s_setprio(1);
#pragma unroll
  for (int m = 0; m < 4; ++m)
#pragma unroll
    for (int n = 0; n < 2; ++n)
      acc[MH * 4 + m][NH * 2 + n] =
          __builtin_amdgcn_mfma_f32_16x16x32_bf16(af[m][KS], bn[n][KS], acc[MH * 4 + m][NH * 2 + n], 0, 0, 0);
  __builtin_amdgcn_s_setprio(0);
}

// MODE 0: fused QKV epilogue. N=4096 tiles: n0<2048 Q (RoPE, same-lane pair),
//         n0 in [2048,3072) K (RoPE), n0>=3072 V^T.
// MODE 1: f32 out = acc + residual (direct store).
template<int NT, int NY, int MODE>
__global__ __launch_bounds__(512) void gemm8p(const bf16* __restrict__ A, const bf16* __restrict__ B,
                                              bf16* __restrict__ Cq, bf16* __restrict__ Ck,
                                              bf16* __restrict__ Cvt, float* __restrict__ fo,
                                              const float* __restrict__ resid, int Nd,
                                              const float* __restrict__ cosb,
                                              const float* __restrict__ sinb) {
  __shared__ char lds[131072];
  const int Ks = NT * 128;  // row stride in BYTES
  const char* Aby = (const char*)A;
  const char* Bby = (const char*)B;

  int wg = blockIdx.x;
  const int chunk = (int)gridDim.x >> 3;
  wg = (wg & 7) * chunk + (wg >> 3);              // XCD-bijective swizzle (grid%8==0)
  const int by = wg % NY, bx = wg / NY;
  const int m0 = bx * 256, n0 = by * 256;

  const int tid = threadIdx.x, lane = tid & 63, wv = tid >> 6;
  const int wm = wv >> 2, wn = wv & 3;
  const int r16 = lane & 15, g = lane >> 4;
  const int xr = (r16 & 7) << 4;
  const int cb0 = (g * 16) ^ xr, cb1 = (64 + g * 16) ^ xr;
  const int rdA = wm * 16384 + r16 * 128;
  const int rdB = 32768 + (wn >> 1) * 16384 + (wn & 1) * 8192 + r16 * 128;

  const char* A0g = Aby + (size_t)m0 * Ks;
  const char* A1g = Aby + (size_t)(m0 + 128) * Ks;
  const char* B0g = Bby + (size_t)n0 * Ks;
  const char* B1g = Bby + (size_t)(n0 + 128) * Ks;

  f32x4 acc[8][4] = {};
  bf16x8 a0[4][2], a1[4][2], bb01[2][2], bb23[2][2];

  auto read_a0bb01 = [&](const char* buf) {
#pragma unroll
    for (int n = 0; n < 2; ++n) bb01[n][0] = *(const bf16x8*)(buf + rdB + n * 2048 + cb0);
#pragma unroll
    for (int n = 0; n < 2; ++n) bb01[n][1] = *(const bf16x8*)(buf + rdB + n * 2048 + cb1);
#pragma unroll
    for (int m = 0; m < 4; ++m) a0[m][0] = *(const bf16x8*)(buf + rdA + m * 2048 + cb0);
#pragma unroll
    for (int m = 0; m < 4; ++m) a0[m][1] = *(const bf16x8*)(buf + rdA + m * 2048 + cb1);
  };

  // ---- prologue: tile0 {A0,A1,B0,B1} -> buf0; tile1 {B0,A0,A1} -> buf1 ----
  stage_half(A0g, Ks, lds + 0,     tid);
  stage_half(A1g, Ks, lds + 16384, tid);
  stage_half(B0g, Ks, lds + 32768, tid);
  stage_half(B1g, Ks, lds + 49152, tid);
  stage_half(B0g + 128, Ks, lds + 65536 + 32768, tid);
  stage_half(A0g + 128, Ks, lds + 65536 + 0,     tid);
  stage_half(A1g + 128, Ks, lds + 65536 + 16384, tid);
  VM6(); BAR();
  read_a0bb01(lds);  // tile 0

  for (int t = 0; t < NT; ++t) {
    const char* bufc = lds + (size_t)(t & 1) * 65536;
    char* bufn = lds + (size_t)((t + 1) & 1) * 65536;
    char* bufs = lds + (size_t)(t & 1) * 65536;
    // ---- P1: a0/bb01 ready; issue bb23 then a1; G1 ----
    LGKM(0);
#pragma unroll
    for (int n = 0; n < 2; ++n) bb23[n][0] = *(const bf16x8*)(bufc + rdB + (2 + n) * 2048 + cb0);
#pragma unroll
    for (int n = 0; n < 2; ++n) bb23[n][1] = *(const bf16x8*)(bufc + rdB + (2 + n) * 2048 + cb1);
#pragma unroll
    for (int m = 0; m < 4; ++m) a1[m][0] = *(const bf16x8*)(bufc + rdA + 8192 + m * 2048 + cb0);
#pragma unroll
    for (int m = 0; m < 4; ++m) a1[m][1] = *(const bf16x8*)(bufc + rdA + 8192 + m * 2048 + cb1);
    SCHED0();
    mfma_burst<0, 0, 0>(a0, bb01, acc);
    mfma_burst<0, 0, 1>(a0, bb01, acc);
    SCHED0(); BAR();
    // ---- P2: bb23 ready; stage B1(t+1); G2 ----
    LGKM(8);
    if (t + 1 < NT)
      stage_half(B1g + (size_t)(t + 1) * 128, Ks, bufn + 49152, tid);
    SCHED0();
    mfma_burst<0, 1, 0>(a0, bb23, acc);
    mfma_burst<0, 1, 1>(a0, bb23, acc);
    SCHED0(); BAR();
    // ---- P3: a1 ready; stage B0(t+2); G3 ----
    LGKM(0);
    if (t + 2 < NT)
      stage_half(B0g + (size_t)(t + 2) * 128, Ks, bufs + 32768, tid);
    SCHED0();
    mfma_burst<1, 0, 0>(a1, bb01, acc);
    mfma_burst<1, 0, 1>(a1, bb01, acc);
    SCHED0(); BAR();
    // ---- P4: counted vmcnt confirms tile t+1; stage A0,A1(t+2); G4 ----
    if (t < NT - 2) { VM2(); } else if (t == NT - 2) { VM0(); }
    if (t + 2 < NT) {
      stage_half(A0g + (size_t)(t + 2) * 128, Ks, bufs + 0,     tid);
      stage_half(A1g + (size_t)(t + 2) * 128, Ks, bufs + 16384, tid);
    }
    SCHED0();
    mfma_burst<1, 1, 0>(a1, bb23, acc);
    mfma_burst<1, 1, 1>(a1, bb23, acc);
    SCHED0(); BAR();
    if (t + 1 < NT) read_a0bb01(bufn);  // read-ahead for next tile
  }

  // ---- epilogue ----
  const int mrow = m0 + wm * 128 + g * 4;
  if constexpr (MODE == 0) {
    if (n0 < 3072) {
      // Fused RoPE, same-lane pairing: acc[i][2jp] holds dim d_e, acc[i][2jp+1]
      // holds d_e+128 (col = wn*64 + jp*32 + r16, bit4 always 0).
      const bool isQ = (n0 < 2048);
      bf16* Cb = isQ ? (Cq + (size_t)0 * 0 + n0) : (Ck + (n0 - 2048));
      const int ld = isQ ? 2048 : 1024;
#pragma unroll
      for (int i = 0; i < 8; ++i)
#pragma unroll
        for (int jp = 0; jp < 2; ++jp) {
          const int col = wn * 64 + jp * 32 + r16;
          const int de = (col & 15) | (((col >> 5) & 7) << 4);
#pragma unroll
          for (int e = 0; e < 4; ++e) {
            const int m = mrow + i * 16 + e;
            const float c  = cosb[(size_t)m * 256 + de];
            const float sn = sinb[(size_t)m * 256 + de];
            const float v0 = acc[i][jp * 2][e];
            const float v1 = acc[i][jp * 2 + 1][e];
            Cb[(size_t)m * ld + de]       = (bf16)(v0 * c - v1 * sn);
            Cb[(size_t)m * ld + de + 128] = (bf16)(v1 * c + v0 * sn);
          }
        }
    } else {
      const int ncol = n0 + wn * 64 + r16;
#pragma unroll
      for (int i = 0; i < 8; ++i)
#pragma unroll
        for (int j = 0; j < 4; ++j)
#pragma unroll
          for (int e = 0; e < 4; ++e) {
            const int m = mrow + i * 16 + e;
            const int n = ncol + j * 16;
            const int b2 = m >> 11, s = m & 2047;
            Cvt[((size_t)b2 * 1024 + (n - 3072)) * SEQ + s] = (bf16)acc[i][j][e];
          }
    }
  } else {
    const int ncol = n0 + wn * 64 + r16;
#pragma unroll
    for (int i = 0; i < 8; ++i)
#pragma unroll
      for (int j = 0; j < 4; ++j)
#pragma unroll
        for (int e = 0; e < 4; ++e) {
          const int m = mrow + i * 16 + e;
          const int n = ncol + j * 16;
          fo[(size_t)m * Nd + n] = acc[i][j][e] + resid[(size_t)m * Nd + n];
        }
  }
}

// ---------------- attention tile loads (K 32x256, V^T 256x32) ----------------
__device__ __forceinline__ void attn_load(const bf16* __restrict__ kgp, const bf16* __restrict__ vgp,
                                          int j0, int t, bf16x8* kr, bf16x8* vr) {
#pragma unroll
  for (int it = 0; it < 4; ++it) {
    const int flat = it * 2048 + t * 8;
    kr[it] = *(const bf16x8*)&kgp[(size_t)((flat >> 8) + j0) * NKV + (flat & 255)];
    vr[it] = *(const bf16x8*)&vgp[(size_t)(flat >> 5) * SEQ + j0 + (flat & 31)];
  }
}

// ---------------- Flash attention: QT=64 (4 waves x 16 rows), KT=32 --------
__global__ __launch_bounds__(256) void attn_kernel(const bf16* __restrict__ q, const bf16* __restrict__ k,
                                                   const bf16* __restrict__ vt, bf16* __restrict__ ao) {
  __shared__ bf16 smem[21248];
  bf16* const qs  = smem;
  bf16* const ksl = smem;
  bf16* const vtl = smem + 8448;
  bf16* const pl  = smem + 18688;
  int qt = blockIdx.x;
  const int h = blockIdx.y, b = blockIdx.z;
  if (b) qt = 31 - qt;
  const int kvh = h >> 1;
  const int t = threadIdx.x, lane = t & 63, w = t >> 6;
  const int r16 = lane & 15, g = lane >> 4;
  const int i_base = qt * 64;

  {
    const bf16* qg = q + ((size_t)(b * SEQ + i_base)) * NQ + h * 256;
#pragma unroll
    for (int it = 0; it < 8; ++it) {
      const int flat = it * 2048 + t * 8;
      const int row = flat >> 8, dd = flat & 255;
      *(bf16x8*)&qs[row * 264 + dd] = *(const bf16x8*)&qg[(size_t)row * NQ + dd];
    }
  }
  __syncthreads();
  bf16x8 aq[8];
#pragma unroll
  for (int c = 0; c < 8; ++c) aq[c] = *(const bf16x8*)&qs[(w * 16 + r16) * 264 + c * 32 + g * 8];

  f32x4 oacc[16] = {};
  float lrun[4] = {0.f, 0.f, 0.f, 0.f};
  int jb = i_base - 1023; if (jb < 0) jb = 0; jb &= ~31;
  const int je = i_base + 63;
  const bf16* kg = k + (size_t)b * SEQ * NKV + kvh * 256;
  const bf16* vg = vt + ((size_t)b * NKV + kvh * 256) * SEQ;

  bf16x8 kr[4], vr[4];
  attn_load(kg, vg, jb, t, kr, vr);

  for (int j0 = jb; j0 <= je; j0 += 32) {
    __syncthreads();
#pragma unroll
    for (int it = 0; it < 4; ++it) {
      const int flat = it * 2048 + t * 8;
      *(bf16x8*)&ksl[(flat >> 8) * 264 + (flat & 255)] = kr[it];
      *(bf16x8*)&vtl[(flat >> 5) * 40 + (flat & 31)] = vr[it];
    }
    __syncthreads();
    const int jn = (j0 + 32 <= je) ? (j0 + 32) : j0;
    attn_load(kg, vg, jn, t, kr, vr);

    f32x4 sc0 = {}, sc1 = {};
#pragma unroll
    for (int c = 0; c < 8; ++c) {
      const bf16x8 b0 = *(const bf16x8*)&ksl[r16 * 264 + c * 32 + g * 8];
      const bf16x8 b1 = *(const bf16x8*)&ksl[(16 + r16) * 264 + c * 32 + g * 8];
      sc0 = __builtin_amdgcn_mfma_f32_16x16x32_bf16(aq[c], b0, sc0, 0, 0, 0);
      sc1 = __builtin_amdgcn_mfma_f32_16x16x32_bf16(aq[c], b1, sc1, 0, 0, 0);
    }
    const bool full = (j0 + 31 <= i_base) && (i_base + 63 - j0 < 1024);
#pragma unroll
    for (int e = 0; e < 4; ++e) {
      const float t0 = __expf(sc0[e] * 0.0025f);
      const float t1 = __expf(sc1[e] * 0.0025f);
      float p0 = __expf(-100.0f / (t0 + 1.0f));
      float p1 = __expf(-100.0f / (t1 + 1.0f));
      if (!full) {
        const int irow = i_base + w * 16 + g * 4 + e;
        const int jg0 = j0 + r16, jg1 = j0 + 16 + r16;
        if (jg0 > irow || irow - jg0 >= 1024) p0 = 0.f;
        if (jg1 > irow || irow - jg1 >= 1024) p1 = 0.f;
      }
      const bf16 b0 = (bf16)p0, b1 = (bf16)p1;
      lrun[e] += (float)b0 + (float)b1;
      pl[w * 640 + (g * 4 + e) * 40 + r16] = b0;
      pl[w * 640 + (g * 4 + e) * 40 + 16 + r16] = b1;
    }
    const bf16x8 pa = *(const bf16x8*)&pl[w * 640 + r16 * 40 + g * 8];
#pragma unroll
    for (int nf = 0; nf < 16; ++nf) {
      const bf16x8 vb = *(const bf16x8*)&vtl[(nf * 16 + r16) * 40 + g * 8];
      oacc[nf] = __builtin_amdgcn_mfma_f32_16x16x32_bf16(pa, vb, oacc[nf], 0, 0, 0);
    }
  }
  float inv[4];
#pragma unroll
  for (int e = 0; e < 4; ++e) {
#pragma unroll
    for (int o = 1; o < 16; o <<= 1) lrun[e] += __shfl_xor(lrun[e], o, 64);
    inv[e] = 1.0f / lrun[e];
  }
  bf16* aor = ao + ((size_t)(b * SEQ + i_base + w * 16)) * NQ + h * 256;
#pragma unroll
  for (int nf = 0; nf < 16; ++nf)
#pragma unroll
    for (int e = 0; e < 4; ++e)
      aor[(size_t)(g * 4 + e) * NQ + nf * 16 + r16] = (bf16)(oacc[nf][e] * inv[e]);
}

extern "C" void kernel_launch(void* const* d_in, const int* in_sizes, int n_in,
                              void* d_out, int out_size, void* d_ws, size_t ws_size,
                              hipStream_t stream) {
  const float* hs   = (const float*)d_in[0];
  const float* cosb = (const float*)d_in[1];
  const float* sinb = (const float*)d_in[2];
  const float* rw   = (const float*)d_in[3];
  const float* Wq   = (const float*)d_in[4];
  const float* Wk   = (const float*)d_in[5];
  const float* Wv   = (const float*)d_in[6];
  const float* Wo   = (const float*)d_in[7];
  float* out = (float*)d_out;
  char* ws = (char*)d_ws;

  bf16* xb   = (bf16*)(ws);             // 4096x2304
  bf16* wqkv = (bf16*)(ws + 18874368);  // [4096][2304]: Wq(2048) | Wk(1024) | Wv(1024)
  bf16* wkb  = wqkv + (size_t)2048 * 2304;
  bf16* wvb  = wqkv + (size_t)3072 * 2304;
  bf16* wob  = (bf16*)(ws + 37748736);  // 2304x2048
  bf16* qg   = (bf16*)(ws + 47185920);  // 4096x2048
  bf16* kg   = (bf16*)(ws + 63963136);  // 4096x1024
  bf16* vtg  = (bf16*)(ws + 72351744);  // [2][1024][2048]
  bf16* ag   = (bf16*)(ws + 80740352);  // 4096x2048

  rmsnorm_kernel<<<4096, 256, 0, stream>>>(hs, rw, xb);
  cvt4_kernel<<<(NW0 + 2 * NW1 + NW3) / 4 / 256, 256, 0, stream>>>(Wq, Wk, Wv, Wo, wqkv, wkb, wvb, wob);
  // QKV: M=4096, N=4096, K=2304 (NT=36), grid 16x16=256, fused RoPE epilogue
  gemm8p<36, 16, 0><<<256, 512, 0, stream>>>(xb, wqkv, qg, kg, vtg, nullptr, nullptr, 4096, cosb, sinb);
  attn_kernel<<<dim3(32, 8, 2), 256, 0, stream>>>(qg, kg, vtg, ag);
  // O-proj: M=4096, N=2304, K=2048 (NT=32), grid 16x9=144, direct f32+resid
  gemm8p<32, 9, 1><<<144, 512, 0, stream>>>(ag, wob, nullptr, nullptr, nullptr, out, hs, 2304, nullptr, nullptr);
}

// Round 14
// 223.899 us; speedup vs baseline: 1.2655x; 1.0663x over previous
//
#include <hip/hip_runtime.h>
#include <cstdint>

typedef __bf16 bf16;
typedef __bf16 bf16x8 __attribute__((ext_vector_type(8)));
typedef __bf16 bf16x4 __attribute__((ext_vector_type(4)));
typedef float  f32x4  __attribute__((ext_vector_type(4)));

#define HIDDEN 2304
#define NQ 2048
#define NKV 1024
#define SEQ 2048

typedef __attribute__((address_space(1))) void gv_t;
typedef __attribute__((address_space(3))) void lv_t;
__device__ __forceinline__ void gld16(const void* g, void* l) {
  __builtin_amdgcn_global_load_lds((gv_t*)g, (lv_t*)l, 16, 0, 0);
}

#define BAR()    asm volatile("s_barrier" ::: "memory")
#define LGKM(n)  asm volatile("s_waitcnt lgkmcnt(" #n ")" ::: "memory")
#define VM6()    asm volatile("s_waitcnt vmcnt(6)" ::: "memory")
#define VM2()    asm volatile("s_waitcnt vmcnt(2)" ::: "memory")
#define VM0()    asm volatile("s_waitcnt vmcnt(0)" ::: "memory")
#define SCHED0() __builtin_amdgcn_sched_barrier(0)

// ---------------- RMSNorm + bf16 cast ----------------
__global__ __launch_bounds__(256) void rmsnorm_kernel(const float* __restrict__ x,
                                                      const float* __restrict__ w,
                                                      bf16* __restrict__ xb) {
  const int row = blockIdx.x, t = threadIdx.x;
  const float* xr = x + (size_t)row * HIDDEN;
  float v[9]; float ss = 0.f;
#pragma unroll
  for (int i = 0; i < 9; ++i) { v[i] = xr[t + i * 256]; ss += v[i] * v[i]; }
#pragma unroll
  for (int o = 32; o; o >>= 1) ss += __shfl_xor(ss, o, 64);
  __shared__ float wss[4];
  if ((t & 63) == 0) wss[t >> 6] = ss;
  __syncthreads();
  ss = wss[0] + wss[1] + wss[2] + wss[3];
  const float rs = rsqrtf(ss * (1.0f / HIDDEN) + 1e-6f);
  bf16* xo = xb + (size_t)row * HIDDEN;
#pragma unroll
  for (int i = 0; i < 9; ++i) xo[t + i * 256] = (bf16)(v[i] * rs * (1.0f + w[t + i * 256]));
}

// ---------------- fused f32 -> bf16 weight convert ----------
// Wq, Wk rows PERMUTED for fused RoPE with SAME-LANE pairing:
// head-dim d -> col(d) = ((d>>4)&7)<<5 | (d>>7)<<4 | (d&15).
// Pair (d, d+128) lands at cols (c, c+16): same lane, adjacent j-fragment.
#define NW0 (2048 * 2304)
#define NW1 (1024 * 2304)
#define NW3 (2304 * 2048)
__global__ __launch_bounds__(256) void cvt4_kernel(const float* __restrict__ s0, const float* __restrict__ s1,
                                                   const float* __restrict__ s2, const float* __restrict__ s3,
                                                   bf16* __restrict__ d0, bf16* __restrict__ d1,
                                                   bf16* __restrict__ d2, bf16* __restrict__ d3) {
  int i = (blockIdx.x * 256 + threadIdx.x) * 4;
  const float* s; bf16* dst; size_t oidx;
  if (i < NW0) {
    s = s0; const int r = i / 2304, c = i % 2304, d = r & 255;
    const int col = (((d >> 4) & 7) << 5) | ((d >> 7) << 4) | (d & 15);
    oidx = (size_t)((r & ~255) | col) * 2304 + c; dst = d0;
  } else if (i < NW0 + NW1) {
    i -= NW0;
    s = s1; const int r = i / 2304, c = i % 2304, d = r & 255;
    const int col = (((d >> 4) & 7) << 5) | ((d >> 7) << 4) | (d & 15);
    oidx = (size_t)((r & ~255) | col) * 2304 + c; dst = d1;
  } else if (i < NW0 + 2 * NW1) {
    i -= NW0 + NW1; s = s2; oidx = i; dst = d2;
  } else {
    i -= NW0 + 2 * NW1; s = s3; oidx = i; dst = d3;
  }
  const float4 f = *(const float4*)(s + i);
  bf16x4 o; o.x = (bf16)f.x; o.y = (bf16)f.y; o.z = (bf16)f.z; o.w = (bf16)f.w;
  *(bf16x4*)(dst + oidx) = o;
}

// ======== 256x256 8-phase GEMM (r8 engine) with fused-RoPE epilogue ========
__device__ __forceinline__ void stage_half(const char* gbase, int stride, char* ldshalf, int tid) {
  const int c2 = ((tid & 7) * 16) ^ (((tid >> 3) & 7) << 4);  // pre-swizzled global col
#pragma unroll
  for (int q = 0; q < 2; ++q) {
    const int r = q * 64 + (tid >> 3);
    gld16(gbase + (size_t)r * stride + c2, ldshalf + q * 8192 + tid * 16);
  }
}

template<int MH, int NH, int KS>
__device__ __forceinline__ void mfma_burst(const bf16x8 (&af)[4][2], const bf16x8 (&bn)[2][2],
                                           f32x4 (&acc)[8][4]) {
  __builtin_amdgcn_s_setprio(1);
#pragma unroll
  for (int m = 0; m < 4; ++m)
#pragma unroll
    for (int n = 0; n < 2; ++n)
      acc[MH * 4 + m][NH * 2 + n] =
          __builtin_amdgcn_mfma_f32_16x16x32_bf16(af[m][KS], bn[n][KS], acc[MH * 4 + m][NH * 2 + n], 0, 0, 0);
  __builtin_amdgcn_s_setprio(0);
}

// MODE 0: fused QKV epilogue. N=4096 tiles: n0<2048 Q (RoPE, same-lane pair),
//         n0 in [2048,3072) K (RoPE), n0>=3072 V^T.
// MODE 1: f32 out = acc + residual (direct store).
template<int NT, int NY, int MODE>
__global__ __launch_bounds__(512) void gemm8p(const bf16* __restrict__ A, const bf16* __restrict__ B,
                                              bf16* __restrict__ Cq, bf16* __restrict__ Ck,
                                              bf16* __restrict__ Cvt, float* __restrict__ fo,
                                              const float* __restrict__ resid, int Nd,
                                              const float* __restrict__ cosb,
                                              const float* __restrict__ sinb) {
  __shared__ char lds[131072];
  const int Ks = NT * 128;  // row stride in BYTES
  const char* Aby = (const char*)A;
  const char* Bby = (const char*)B;

  int wg = blockIdx.x;
  const int chunk = (int)gridDim.x >> 3;
  wg = (wg & 7) * chunk + (wg >> 3);              // XCD-bijective swizzle (grid%8==0)
  const int by = wg % NY, bx = wg / NY;
  const int m0 = bx * 256, n0 = by * 256;

  const int tid = threadIdx.x, lane = tid & 63, wv = tid >> 6;
  const int wm = wv >> 2, wn = wv & 3;
  const int r16 = lane & 15, g = lane >> 4;
  const int xr = (r16 & 7) << 4;
  const int cb0 = (g * 16) ^ xr, cb1 = (64 + g * 16) ^ xr;
  const int rdA = wm * 16384 + r16 * 128;
  const int rdB = 32768 + (wn >> 1) * 16384 + (wn & 1) * 8192 + r16 * 128;

  const char* A0g = Aby + (size_t)m0 * Ks;
  const char* A1g = Aby + (size_t)(m0 + 128) * Ks;
  const char* B0g = Bby + (size_t)n0 * Ks;
  const char* B1g = Bby + (size_t)(n0 + 128) * Ks;

  f32x4 acc[8][4] = {};
  bf16x8 a0[4][2], a1[4][2], bb01[2][2], bb23[2][2];

  auto read_a0bb01 = [&](const char* buf) {
#pragma unroll
    for (int n = 0; n < 2; ++n) bb01[n][0] = *(const bf16x8*)(buf + rdB + n * 2048 + cb0);
#pragma unroll
    for (int n = 0; n < 2; ++n) bb01[n][1] = *(const bf16x8*)(buf + rdB + n * 2048 + cb1);
#pragma unroll
    for (int m = 0; m < 4; ++m) a0[m][0] = *(const bf16x8*)(buf + rdA + m * 2048 + cb0);
#pragma unroll
    for (int m = 0; m < 4; ++m) a0[m][1] = *(const bf16x8*)(buf + rdA + m * 2048 + cb1);
  };

  // ---- prologue: tile0 {A0,A1,B0,B1} -> buf0; tile1 {B0,A0,A1} -> buf1 ----
  stage_half(A0g, Ks, lds + 0,     tid);
  stage_half(A1g, Ks, lds + 16384, tid);
  stage_half(B0g, Ks, lds + 32768, tid);
  stage_half(B1g, Ks, lds + 49152, tid);
  stage_half(B0g + 128, Ks, lds + 65536 + 32768, tid);
  stage_half(A0g + 128, Ks, lds + 65536 + 0,     tid);
  stage_half(A1g + 128, Ks, lds + 65536 + 16384, tid);
  VM6(); BAR();
  read_a0bb01(lds);  // tile 0

  for (int t = 0; t < NT; ++t) {
    const char* bufc = lds + (size_t)(t & 1) * 65536;
    char* bufn = lds + (size_t)((t + 1) & 1) * 65536;
    char* bufs = lds + (size_t)(t & 1) * 65536;
    // ---- P1: a0/bb01 ready; issue bb23 then a1; G1 ----
    LGKM(0);
#pragma unroll
    for (int n = 0; n < 2; ++n) bb23[n][0] = *(const bf16x8*)(bufc + rdB + (2 + n) * 2048 + cb0);
#pragma unroll
    for (int n = 0; n < 2; ++n) bb23[n][1] = *(const bf16x8*)(bufc + rdB + (2 + n) * 2048 + cb1);
#pragma unroll
    for (int m = 0; m < 4; ++m) a1[m][0] = *(const bf16x8*)(bufc + rdA + 8192 + m * 2048 + cb0);
#pragma unroll
    for (int m = 0; m < 4; ++m) a1[m][1] = *(const bf16x8*)(bufc + rdA + 8192 + m * 2048 + cb1);
    SCHED0();
    mfma_burst<0, 0, 0>(a0, bb01, acc);
    mfma_burst<0, 0, 1>(a0, bb01, acc);
    SCHED0(); BAR();
    // ---- P2: bb23 ready; stage B1(t+1); G2 ----
    LGKM(8);
    if (t + 1 < NT)
      stage_half(B1g + (size_t)(t + 1) * 128, Ks, bufn + 49152, tid);
    SCHED0();
    mfma_burst<0, 1, 0>(a0, bb23, acc);
    mfma_burst<0, 1, 1>(a0, bb23, acc);
    SCHED0(); BAR();
    // ---- P3: a1 ready; stage B0(t+2); G3 ----
    LGKM(0);
    if (t + 2 < NT)
      stage_half(B0g + (size_t)(t + 2) * 128, Ks, bufs + 32768, tid);
    SCHED0();
    mfma_burst<1, 0, 0>(a1, bb01, acc);
    mfma_burst<1, 0, 1>(a1, bb01, acc);
    SCHED0(); BAR();
    // ---- P4: counted vmcnt confirms tile t+1; stage A0,A1(t+2); G4 ----
    if (t < NT - 2) { VM2(); } else if (t == NT - 2) { VM0(); }
    if (t + 2 < NT) {
      stage_half(A0g + (size_t)(t + 2) * 128, Ks, bufs + 0,     tid);
      stage_half(A1g + (size_t)(t + 2) * 128, Ks, bufs + 16384, tid);
    }
    SCHED0();
    mfma_burst<1, 1, 0>(a1, bb23, acc);
    mfma_burst<1, 1, 1>(a1, bb23, acc);
    SCHED0(); BAR();
    if (t + 1 < NT) read_a0bb01(bufn);  // read-ahead for next tile
  }

  // ---- epilogue ----
  const int mrow = m0 + wm * 128 + g * 4;
  if constexpr (MODE == 0) {
    if (n0 < 3072) {
      // Fused RoPE, same-lane pairing: acc[i][2jp] holds dim d_e, acc[i][2jp+1]
      // holds d_e+128 (col = wn*64 + jp*32 + r16, bit4 always 0).
      const bool isQ = (n0 < 2048);
      bf16* Cb = isQ ? (Cq + (size_t)0 * 0 + n0) : (Ck + (n0 - 2048));
      const int ld = isQ ? 2048 : 1024;
#pragma unroll
      for (int i = 0; i < 8; ++i)
#pragma unroll
        for (int jp = 0; jp < 2; ++jp) {
          const int col = wn * 64 + jp * 32 + r16;
          const int de = (col & 15) | (((col >> 5) & 7) << 4);
#pragma unroll
          for (int e = 0; e < 4; ++e) {
            const int m = mrow + i * 16 + e;
            const float c  = cosb[(size_t)m * 256 + de];
            const float sn = sinb[(size_t)m * 256 + de];
            const float v0 = acc[i][jp * 2][e];
            const float v1 = acc[i][jp * 2 + 1][e];
            Cb[(size_t)m * ld + de]       = (bf16)(v0 * c - v1 * sn);
            Cb[(size_t)m * ld + de + 128] = (bf16)(v1 * c + v0 * sn);
          }
        }
    } else {
      const int ncol = n0 + wn * 64 + r16;
#pragma unroll
      for (int i = 0; i < 8; ++i)
#pragma unroll
        for (int j = 0; j < 4; ++j)
#pragma unroll
          for (int e = 0; e < 4; ++e) {
            const int m = mrow + i * 16 + e;
            const int n = ncol + j * 16;
            const int b2 = m >> 11, s = m & 2047;
            Cvt[((size_t)b2 * 1024 + (n - 3072)) * SEQ + s] = (bf16)acc[i][j][e];
          }
    }
  } else {
    const int ncol = n0 + wn * 64 + r16;
#pragma unroll
    for (int i = 0; i < 8; ++i)
#pragma unroll
      for (int j = 0; j < 4; ++j)
#pragma unroll
        for (int e = 0; e < 4; ++e) {
          const int m = mrow + i * 16 + e;
          const int n = ncol + j * 16;
          fo[(size_t)m * Nd + n] = acc[i][j][e] + resid[(size_t)m * Nd + n];
        }
  }
}

// ---------------- attention tile loads (K 32x256, V^T 256x32) ----------------
__device__ __forceinline__ void attn_load(const bf16* __restrict__ kgp, const bf16* __restrict__ vgp,
                                          int j0, int t, bf16x8* kr, bf16x8* vr) {
#pragma unroll
  for (int it = 0; it < 4; ++it) {
    const int flat = it * 2048 + t * 8;
    kr[it] = *(const bf16x8*)&kgp[(size_t)((flat >> 8) + j0) * NKV + (flat & 255)];
    vr[it] = *(const bf16x8*)&vgp[(size_t)(flat >> 5) * SEQ + j0 + (flat & 31)];
  }
}

// ---------------- Flash attention: QT=64 (4 waves x 16 rows), KT=32 --------
__global__ __launch_bounds__(256) void attn_kernel(const bf16* __restrict__ q, const bf16* __restrict__ k,
                                                   const bf16* __restrict__ vt, bf16* __restrict__ ao) {
  __shared__ bf16 smem[21248];
  bf16* const qs  = smem;
  bf16* const ksl = smem;
  bf16* const vtl = smem + 8448;
  bf16* const pl  = smem + 18688;
  int qt = blockIdx.x;
  const int h = blockIdx.y, b = blockIdx.z;
  if (b) qt = 31 - qt;
  const int kvh = h >> 1;
  const int t = threadIdx.x, lane = t & 63, w = t >> 6;
  const int r16 = lane & 15, g = lane >> 4;
  const int i_base = qt * 64;

  {
    const bf16* qg = q + ((size_t)(b * SEQ + i_base)) * NQ + h * 256;
#pragma unroll
    for (int it = 0; it < 8; ++it) {
      const int flat = it * 2048 + t * 8;
      const int row = flat >> 8, dd = flat & 255;
      *(bf16x8*)&qs[row * 264 + dd] = *(const bf16x8*)&qg[(size_t)row * NQ + dd];
    }
  }
  __syncthreads();
  bf16x8 aq[8];
#pragma unroll
  for (int c = 0; c < 8; ++c) aq[c] = *(const bf16x8*)&qs[(w * 16 + r16) * 264 + c * 32 + g * 8];

  f32x4 oacc[16] = {};
  float lrun[4] = {0.f, 0.f, 0.f, 0.f};
  int jb = i_base - 1023; if (jb < 0) jb = 0; jb &= ~31;
  const int je = i_base + 63;
  const bf16* kg = k + (size_t)b * SEQ * NKV + kvh * 256;
  const bf16* vg = vt + ((size_t)b * NKV + kvh * 256) * SEQ;

  bf16x8 kr[4], vr[4];
  attn_load(kg, vg, jb, t, kr, vr);

  for (int j0 = jb; j0 <= je; j0 += 32) {
    __syncthreads();
#pragma unroll
    for (int it = 0; it < 4; ++it) {
      const int flat = it * 2048 + t * 8;
      *(bf16x8*)&ksl[(flat >> 8) * 264 + (flat & 255)] = kr[it];
      *(bf16x8*)&vtl[(flat >> 5) * 40 + (flat & 31)] = vr[it];
    }
    __syncthreads();
    const int jn = (j0 + 32 <= je) ? (j0 + 32) : j0;
    attn_load(kg, vg, jn, t, kr, vr);

    f32x4 sc0 = {}, sc1 = {};
#pragma unroll
    for (int c = 0; c < 8; ++c) {
      const bf16x8 b0 = *(const bf16x8*)&ksl[r16 * 264 + c * 32 + g * 8];
      const bf16x8 b1 = *(const bf16x8*)&ksl[(16 + r16) * 264 + c * 32 + g * 8];
      sc0 = __builtin_amdgcn_mfma_f32_16x16x32_bf16(aq[c], b0, sc0, 0, 0, 0);
      sc1 = __builtin_amdgcn_mfma_f32_16x16x32_bf16(aq[c], b1, sc1, 0, 0, 0);
    }
    const bool full = (j0 + 31 <= i_base) && (i_base + 63 - j0 < 1024);
#pragma unroll
    for (int e = 0; e < 4; ++e) {
      const float t0 = __expf(sc0[e] * 0.0025f);
      const float t1 = __expf(sc1[e] * 0.0025f);
      float p0 = __expf(-100.0f / (t0 + 1.0f));
      float p1 = __expf(-100.0f / (t1 + 1.0f));
      if (!full) {
        const int irow = i_base + w * 16 + g * 4 + e;
        const int jg0 = j0 + r16, jg1 = j0 + 16 + r16;
        if (jg0 > irow || irow - jg0 >= 1024) p0 = 0.f;
        if (jg1 > irow || irow - jg1 >= 1024) p1 = 0.f;
      }
      const bf16 b0 = (bf16)p0, b1 = (bf16)p1;
      lrun[e] += (float)b0 + (float)b1;
      pl[w * 640 + (g * 4 + e) * 40 + r16] = b0;
      pl[w * 640 + (g * 4 + e) * 40 + 16 + r16] = b1;
    }
    const bf16x8 pa = *(const bf16x8*)&pl[w * 640 + r16 * 40 + g * 8];
#pragma unroll
    for (int nf = 0; nf < 16; ++nf) {
      const bf16x8 vb = *(const bf16x8*)&vtl[(nf * 16 + r16) * 40 + g * 8];
      oacc[nf] = __builtin_amdgcn_mfma_f32_16x16x32_bf16(pa, vb, oacc[nf], 0, 0, 0);
    }
  }
  float inv[4];
#pragma unroll
  for (int e = 0; e < 4; ++e) {
#pragma unroll
    for (int o = 1; o < 16; o <<= 1) lrun[e] += __shfl_xor(lrun[e], o, 64);
    inv[e] = 1.0f / lrun[e];
  }
  bf16* aor = ao + ((size_t)(b * SEQ + i_base + w * 16)) * NQ + h * 256;
#pragma unroll
  for (int nf = 0; nf < 16; ++nf)
#pragma unroll
    for (int e = 0; e < 4; ++e)
      aor[(size_t)(g * 4 + e) * NQ + nf * 16 + r16] = (bf16)(oacc[nf][e] * inv[e]);
}

extern "C" void kernel_launch(void* const* d_in, const int* in_sizes, int n_in,
                              void* d_out, int out_size, void* d_ws, size_t ws_size,
                              hipStream_t stream) {
  const float* hs   = (const float*)d_in[0];
  const float* cosb = (const float*)d_in[1];
  const float* sinb = (const float*)d_in[2];
  const float* rw   = (const float*)d_in[3];
  const float* Wq   = (const float*)d_in[4];
  const float* Wk   = (const float*)d_in[5];
  const float* Wv   = (const float*)d_in[6];
  const float* Wo   = (const float*)d_in[7];
  float* out = (float*)d_out;
  char* ws = (char*)d_ws;

  bf16* xb   = (bf16*)(ws);             // 4096x2304
  bf16* wqkv = (bf16*)(ws + 18874368);  // [4096][2304]: Wq(2048) | Wk(1024) | Wv(1024)
  bf16* wkb  = wqkv + (size_t)2048 * 2304;
  bf16* wvb  = wqkv + (size_t)3072 * 2304;
  bf16* wob  = (bf16*)(ws + 37748736);  // 2304x2048
  bf16* qg   = (bf16*)(ws + 47185920);  // 4096x2048
  bf16* kg   = (bf16*)(ws + 63963136);  // 4096x1024
  bf16* vtg  = (bf16*)(ws + 72351744);  // [2][1024][2048]
  bf16* ag   = (bf16*)(ws + 80740352);  // 4096x2048

  rmsnorm_kernel<<<4096, 256, 0, stream>>>(hs, rw, xb);
  cvt4_kernel<<<(NW0 + 2 * NW1 + NW3) / 4 / 256, 256, 0, stream>>>(Wq, Wk, Wv, Wo, wqkv, wkb, wvb, wob);
  // QKV: M=4096, N=4096, K=2304 (NT=36), grid 16x16=256, fused RoPE epilogue
  gemm8p<36, 16, 0><<<256, 512, 0, stream>>>(xb, wqkv, qg, kg, vtg, nullptr, nullptr, 4096, cosb, sinb);
  attn_kernel<<<dim3(32, 8, 2), 256, 0, stream>>>(qg, kg, vtg, ag);
  // O-proj: M=4096, N=2304, K=2048 (NT=32), grid 16x9=144, direct f32+resid
  gemm8p<32, 9, 1><<<144, 512, 0, stream>>>(ag, wob, nullptr, nullptr, nullptr, out, hs, 2304, nullptr, nullptr);
}